// Round 2
// baseline (138.572 us; speedup 1.0000x reference)
//
#include <hip/hip_runtime.h>
#include <math.h>

// Problem constants (fixed by reference)
//  B=128, N=32, M=64, OBS=128, ACT=16, D_QK=128, D_AV=64, F_IN=144, H=64
// Outputs concatenated: value [B,32,32] @0, ret_weight [B,32,32] @131072,
// weight_other [B,32,64] @262144.
//
// Workspace (floats), 1,081,344 floats = 4.125 MB:
#define WS_WQK   0         // [128][128]
#define WS_WQKO  16384     // [128][128]
#define WS_AVA   32768     // [B][32][64]
#define WS_AVO   294912    // [B][64][64]
#define WS_DPROJ 819200    // [B][32][64]

#define INV_SQRT_DK 0.08838834764831845f  // 1/sqrt(128)

__device__ __forceinline__ float dot4(float4 a, float4 b) {
  return a.x*b.x + a.y*b.y + a.z*b.z + a.w*b.w;
}
__device__ __forceinline__ void fma4(float4& a, const float4 w, const float s) {
  a.x += w.x*s; a.y += w.y*s; a.z += w.z*s; a.w += w.w*s;
}

// ---------------------------------------------------------------------------
// K1: independent pre-work. grid 800 (was 416 -> 1.6 blk/CU; now 3.1 blk/CU):
//   [0,32)     Wqk / Wqko fusion tiles (32x32 out each)
//   [32,288)   avA + delta + dproj per (b, j-half)   (16 rows each)
//   [288,800)  avO per (b, m-quarter)                (16 rows each, no LDS)
// ---------------------------------------------------------------------------
__global__ __launch_bounds__(256, 4) void k1_pre(
    const float* __restrict__ g_states, const float* __restrict__ g_pol,
    const float* __restrict__ g_act, const float* __restrict__ g_so,
    const float* __restrict__ g_ao,
    const float* __restrict__ Wq, const float* __restrict__ Wk,
    const float* __restrict__ Wqo, const float* __restrict__ Wko,
    const float* __restrict__ W_av, const float* __restrict__ W_avo,
    const float* __restrict__ W_f1, float* __restrict__ ws)
{
  __shared__ __align__(16) float pool[8448];   // 33 KB -> 4 blocks/CU cap
  const int t = threadIdx.x;
  int blk = blockIdx.x;

  if (blk < 32) {
    // ---- weight fusion: Wqk[c][e] = sum_d Wq[c,d]*Wk[e,d] ----------------
    const float* A; const float* Bm; float* O;
    if (blk < 16) { A = Wq;  Bm = Wk;  O = ws + WS_WQK; }
    else          { A = Wqo; Bm = Wko; O = ws + WS_WQKO; blk -= 16; }
    const int tr = (blk >> 2) << 5;   // output row tile (c)
    const int tc = (blk & 3) << 5;    // output col tile (e)
    float* sA = pool;                 // [32][132]
    float* sB = pool + 4224;          // [32][132]
    const float4* a4 = (const float4*)(A + tr * 128);
    const float4* b4 = (const float4*)(Bm + tc * 128);
    #pragma unroll
    for (int u = 0; u < 4; ++u) {
      int f = t + u * 256;
      int r = f >> 5, c4 = f & 31;
      *(float4*)(sA + r*132 + c4*4) = a4[f];
      *(float4*)(sB + r*132 + c4*4) = b4[f];
    }
    __syncthreads();
    const int e = t & 31, cl0 = t >> 5;
    float acc[4] = {0,0,0,0};
    #pragma unroll 4
    for (int d4 = 0; d4 < 32; ++d4) {
      float4 bv = *(const float4*)(sB + e*132 + d4*4);
      #pragma unroll
      for (int rr = 0; rr < 4; ++rr) {
        float4 av = *(const float4*)(sA + (cl0 + rr*8)*132 + d4*4);
        acc[rr] += dot4(av, bv);
      }
    }
    #pragma unroll
    for (int rr = 0; rr < 4; ++rr)
      O[(tr + cl0 + rr*8)*128 + tc + e] = acc[rr];
    return;
  }
  blk -= 32;

  if (blk < 256) {
    // ---- avA + delta + dproj per (b, j-half): 16 rows --------------------
    const int b  = blk >> 1;
    const int jh = blk & 1;            // row half: rows jh*16 .. +16
    float* s_pre = pool;               // [16][132]: pre-act A at +0, P at +64
    float* s_dl  = pool + 2112;        // delta [16][68]
    {
      const int wv_  = t >> 6;         // wave 0..3
      const int ap   = wv_ & 1;        // 0 = actions, 1 = policies
      const int rq   = wv_ >> 1;       // 8-row group within the half
      const int lane = t & 63;         // d column
      const float* gs = g_states + b*4096 + (jh*16 + rq*8)*128;
      const float* gt = (ap ? g_pol : g_act) + b*512 + (jh*16 + rq*8)*16;
      float acc[8];
      #pragma unroll
      for (int r = 0; r < 8; ++r) acc[r] = 0.f;
      #pragma unroll 4
      for (int c4 = 0; c4 < 32; ++c4) {          // shared c < 128
        const float w0 = W_av[(c4*4+0)*64 + lane];
        const float w1 = W_av[(c4*4+1)*64 + lane];
        const float w2 = W_av[(c4*4+2)*64 + lane];
        const float w3 = W_av[(c4*4+3)*64 + lane];
        #pragma unroll
        for (int r = 0; r < 8; ++r) {
          float4 sv = *(const float4*)(gs + r*128 + c4*4);  // wave-uniform
          acc[r] += sv.x*w0 + sv.y*w1 + sv.z*w2 + sv.w*w3;
        }
      }
      #pragma unroll
      for (int c4 = 0; c4 < 4; ++c4) {           // tail c in [128,144)
        const float w0 = W_av[(128 + c4*4+0)*64 + lane];
        const float w1 = W_av[(128 + c4*4+1)*64 + lane];
        const float w2 = W_av[(128 + c4*4+2)*64 + lane];
        const float w3 = W_av[(128 + c4*4+3)*64 + lane];
        #pragma unroll
        for (int r = 0; r < 8; ++r) {
          float4 sv = *(const float4*)(gt + r*16 + c4*4);
          acc[r] += sv.x*w0 + sv.y*w1 + sv.z*w2 + sv.w*w3;
        }
      }
      #pragma unroll
      for (int r = 0; r < 8; ++r)
        s_pre[(rq*8 + r)*132 + ap*64 + lane] = acc[r];
    }
    __syncthreads();
    {
      // combine: avA = tanh(preA); delta = tanh(preP) - avA
      const int r = t >> 4, d0 = (t & 15) << 2;   // 16 rows x 16 f4-cols
      float4 a0 = *(const float4*)(s_pre + r*132 + d0);
      float4 p0 = *(const float4*)(s_pre + r*132 + 64 + d0);
      float4 va0, dl0;
      va0.x = tanhf(a0.x); va0.y = tanhf(a0.y); va0.z = tanhf(a0.z); va0.w = tanhf(a0.w);
      dl0.x = tanhf(p0.x) - va0.x; dl0.y = tanhf(p0.y) - va0.y;
      dl0.z = tanhf(p0.z) - va0.z; dl0.w = tanhf(p0.w) - va0.w;
      *(float4*)(ws + WS_AVA + b*2048 + (jh*16 + r)*64 + d0) = va0;
      *(float4*)(s_dl + r*68 + d0) = dl0;
    }
    __syncthreads();
    {
      // dproj[j][h] = sum_d delta[j][d] * W_f1[d][h]
      const int h = t & 63;
      const int j0 = (t >> 6) << 2;     // 4 rows per thread
      float acc[4] = {0,0,0,0};
      #pragma unroll 4
      for (int d4 = 0; d4 < 16; ++d4) {
        float w0 = W_f1[(d4*4+0)*64 + h];
        float w1 = W_f1[(d4*4+1)*64 + h];
        float w2 = W_f1[(d4*4+2)*64 + h];
        float w3 = W_f1[(d4*4+3)*64 + h];
        #pragma unroll
        for (int q = 0; q < 4; ++q) {
          float4 dv = *(const float4*)(s_dl + (j0+q)*68 + d4*4);
          acc[q] += dv.x*w0 + dv.y*w1 + dv.z*w2 + dv.w*w3;
        }
      }
      #pragma unroll
      for (int q = 0; q < 4; ++q)
        ws[WS_DPROJ + b*2048 + (jh*16 + j0+q)*64 + h] = acc[q];
    }
    return;
  }
  blk -= 256;

  // ---- avO per (b, 16-row quarter): wave = 4-row group, lane = d ---------
  {
    const int b = blk >> 2, m0 = (blk & 3) << 4;
    const int wv_  = t >> 6;            // 0..3: 4-row group
    const int lane = t & 63;
    const float* gso = g_so + (b*64 + m0 + wv_*4) * 128;
    const float* gao = g_ao + (b*64 + m0 + wv_*4) * 16;
    float acc[4] = {0.f, 0.f, 0.f, 0.f};
    #pragma unroll 4
    for (int c4 = 0; c4 < 32; ++c4) {
      const float w0 = W_avo[(c4*4+0)*64 + lane];
      const float w1 = W_avo[(c4*4+1)*64 + lane];
      const float w2 = W_avo[(c4*4+2)*64 + lane];
      const float w3 = W_avo[(c4*4+3)*64 + lane];
      #pragma unroll
      for (int r = 0; r < 4; ++r) {
        float4 sv = *(const float4*)(gso + r*128 + c4*4);  // wave-uniform
        acc[r] += sv.x*w0 + sv.y*w1 + sv.z*w2 + sv.w*w3;
      }
    }
    #pragma unroll
    for (int c4 = 0; c4 < 4; ++c4) {
      const float w0 = W_avo[(128 + c4*4+0)*64 + lane];
      const float w1 = W_avo[(128 + c4*4+1)*64 + lane];
      const float w2 = W_avo[(128 + c4*4+2)*64 + lane];
      const float w3 = W_avo[(128 + c4*4+3)*64 + lane];
      #pragma unroll
      for (int r = 0; r < 4; ++r) {
        float4 sv = *(const float4*)(gao + r*16 + c4*4);
        acc[r] += sv.x*w0 + sv.y*w1 + sv.z*w2 + sv.w*w3;
      }
    }
    #pragma unroll
    for (int r = 0; r < 4; ++r)
      ws[WS_AVO + b*4096 + (m0 + wv_*4 + r)*64 + lane] = tanhf(acc[r]);
  }
}

// ---------------------------------------------------------------------------
// K2: everything after pre-work, per (b, i-octile). grid 512 x 512 threads
// (was 256 threads): 2 blocks/CU co-resident -> 16 waves/CU = 4 waves/SIMD,
// every phase remapped so per-thread critical path halves.
// LDS pool (floats), 17472 = 68.25 KB (2 blocks/CU):
//   A    @0     [4352]: states [32][132] / so tiles [32][132] / avO [64][68]
//   RED  @4352  [8448]: ph2 partials [4][8][66]xf4; later avA[32][68]@4352,
//                        dproj [32][68] @6528
//   P    @12800 [2144]: [8][268]  (P1 cols 0..127, P2 cols 128..255);
//                        scratch for wavo partial (mh=1) in ph7
//   w    @14944 [288] : [8][36]
//   wo   @15232 [544] : [8][68]
//   S    @15776 [544] : [8][68]
//   wavo @16320 [544]
//   base @16864 [544]
//   wf2  @17408 [64]
// ---------------------------------------------------------------------------
__global__ __launch_bounds__(512, 4) void k2_main(
    const float* __restrict__ g_states, const float* __restrict__ g_so,
    const float* __restrict__ W_f1, const float* __restrict__ W_f2,
    const float* __restrict__ ws, float* __restrict__ out)
{
  __shared__ __align__(16) float pool[17472];
  float* s_st   = pool;
  float* s_red  = pool + 4352;
  float* s_avA  = pool + 4352;     // alias RED (dead after ph2 reduce)
  float* s_dp   = pool + 6528;     // alias RED
  float* s_avO  = pool;            // alias A (dead after ph5)
  float* s_P    = pool + 12800;
  float* s_w    = pool + 14944;
  float* s_wo   = pool + 15232;
  float* s_S    = pool + 15776;
  float* s_wavo = pool + 16320;
  float* s_base = pool + 16864;
  float* s_wf2  = pool + 17408;

  const int t = threadIdx.x;
  const int b = blockIdx.x >> 2;
  const int i0 = (blockIdx.x & 3) << 3;

  // ---- ph1: stage states (for ph3 j-side), wf2 ---------------------------
  {
    const float4* gs4 = (const float4*)(g_states + b * 4096);
    #pragma unroll
    for (int u = 0; u < 2; ++u) {
      int f = t + u * 512;
      int r = f >> 5, c4 = f & 31;
      *(float4*)(s_st + r*132 + c4*4) = gs4[f];
    }
    if (t < 16) *(float4*)(s_wf2 + t*4) = ((const float4*)W_f2)[t];
  }

  // ---- ph2: P = states[i0..+8] @ [Wqk|Wqko] ------------------------------
  // wave = (K-chunk, row-half); lane = f4-column of [P1|P2]. Per-thread
  // work halved vs 256-thread version (4 rows, 512 FMA).
  {
    const int wave = t >> 6;             // 0..7
    const int kc   = wave & 3;           // K chunk (32 c each)
    const int rh   = wave >> 2;          // row half (4 rows)
    const int col  = t & 63;             // <32: Wqk/P1, >=32: Wqko/P2
    const float* Wp = (col < 32) ? (ws + WS_WQK + col*4)
                                 : (ws + WS_WQKO + (col-32)*4);
    const float* srow = g_states + b*4096 + (i0 + rh*4)*128 + kc*32;
    float4 acc[4];
    #pragma unroll
    for (int r = 0; r < 4; ++r) acc[r] = make_float4(0.f,0.f,0.f,0.f);
    #pragma unroll 2
    for (int c4 = 0; c4 < 8; ++c4) {
      float4 sv[4];
      #pragma unroll
      for (int r = 0; r < 4; ++r)
        sv[r] = *(const float4*)(srow + r*128 + c4*4);    // wave-uniform
      #pragma unroll
      for (int k = 0; k < 4; ++k) {
        float4 wv = *(const float4*)(Wp + (kc*32 + c4*4 + k)*128);
        #pragma unroll
        for (int r = 0; r < 4; ++r)
          fma4(acc[r], wv, ((const float*)&sv[r])[k]);
      }
    }
    #pragma unroll
    for (int r = 0; r < 4; ++r)
      *(float4*)(s_red + ((kc*8 + rh*4 + r)*66 + col)*4) = acc[r];
  }
  __syncthreads();
  {
    // reduce 4 K-chunk partials -> P [8][268]; 512 threads = [8 rows][64 f4]
    const int r = t >> 6, col = t & 63;
    float4 a0 = *(const float4*)(s_red + ((0*8 + r)*66 + col)*4);
    float4 a1 = *(const float4*)(s_red + ((1*8 + r)*66 + col)*4);
    float4 a2 = *(const float4*)(s_red + ((2*8 + r)*66 + col)*4);
    float4 a3 = *(const float4*)(s_red + ((3*8 + r)*66 + col)*4);
    float4 s4;
    s4.x = (a0.x + a1.x) + (a2.x + a3.x);
    s4.y = (a0.y + a1.y) + (a2.y + a3.y);
    s4.z = (a0.z + a1.z) + (a2.z + a3.z);
    s4.w = (a0.w + a1.w) + (a2.w + a3.w);
    *(float4*)(s_P + r*268 + col*4) = s4;
  }
  __syncthreads();

  // ---- ph3: self scores + register softmax + write ret_weight ------------
  // (r, j, e-half) per thread; halves combined via shfl_xor(32).
  {
    const int r = t >> 6, j = t & 31, half = (t >> 5) & 1;
    const int e0 = half << 4;
    float acc = 0.f;
    #pragma unroll 8
    for (int e4 = 0; e4 < 16; ++e4) {
      float4 p4  = *(const float4*)(s_P + r*268 + (e0 + e4)*4);
      float4 st4 = *(const float4*)(s_st + j*132 + (e0 + e4)*4);
      acc += dot4(p4, st4);
    }
    acc += __shfl_xor(acc, 32, 64);
    acc *= INV_SQRT_DK;
    float mx = acc;
    for (int off = 16; off; off >>= 1) mx = fmaxf(mx, __shfl_xor(mx, off, 32));
    float ev = __expf(acc - mx);
    float sum = ev;
    for (int off = 16; off; off >>= 1) sum += __shfl_xor(sum, off, 32);
    float wn = ev / sum;
    if (half == 0) {
      out[131072 + b*1024 + (i0 + r)*32 + j] = wn;
      s_w[r*36 + j] = wn;
    }
  }
  __syncthreads();   // protect s_st reads from ph4's overwrite

  // ---- ph4/5: other scores over two states_other tiles -------------------
  for (int tt = 0; tt < 2; ++tt) {
    const float4* gt4 = (const float4*)(g_so + (b*64 + tt*32) * 128);
    #pragma unroll
    for (int u = 0; u < 2; ++u) {
      int f = t + u * 512;
      int r = f >> 5, c4 = f & 31;
      *(float4*)(s_st + r*132 + c4*4) = gt4[f];
    }
    __syncthreads();
    const int r = t >> 6, m = t & 31, half = (t >> 5) & 1;
    const int c0 = half << 4;
    float acc = 0.f;
    #pragma unroll 8
    for (int c4 = 0; c4 < 16; ++c4) {
      float4 p4  = *(const float4*)(s_P + r*268 + 128 + (c0 + c4)*4);
      float4 st4 = *(const float4*)(s_st + m*132 + (c0 + c4)*4);
      acc += dot4(p4, st4);
    }
    acc += __shfl_xor(acc, 32, 64);
    if (half == 0) s_wo[r*68 + tt*32 + m] = acc * INV_SQRT_DK;
    __syncthreads();
  }

  // ---- ph6: softmax wo + write weight_other; stage avA/avO/dproj ---------
  {
    const int r = t >> 6, l = t & 63;          // 512 threads = [8][64]
    float v = s_wo[r*68 + l];
    float mx = v;
    for (int off = 32; off; off >>= 1) mx = fmaxf(mx, __shfl_xor(mx, off, 64));
    float ev = __expf(v - mx);
    float sum = ev;
    for (int off = 32; off; off >>= 1) sum += __shfl_xor(sum, off, 64);
    float wn = ev / sum;
    out[262144 + b*2048 + (i0 + r)*64 + l] = wn;
    s_wo[r*68 + l] = wn;
  }
  {
    int f = t;                                  // 512 f4 each
    int k = f >> 4, dq = f & 15;
    *(float4*)(s_avA + k*68 + dq*4) = ((const float4*)(ws + WS_AVA + b*2048))[f];
    *(float4*)(s_dp  + k*68 + dq*4) = ((const float4*)(ws + WS_DPROJ + b*2048))[f];
  }
  #pragma unroll
  for (int u = 0; u < 2; ++u) {
    int f = t + u * 512;
    int m = f >> 4, dq = f & 15;
    *(float4*)(s_avO + m*68 + dq*4) = ((const float4*)(ws + WS_AVO + b*4096))[f];
  }
  __syncthreads();

  // ---- ph7: S = w @ avA (t<128); wavo = wo @ avO split over m (t<384) ----
  if (t < 128) {
    const int i = t >> 4, dq = (t & 15) << 2;
    float4 acc = {0,0,0,0};
    #pragma unroll 4
    for (int k = 0; k < 32; ++k) {
      float4 a4 = *(const float4*)(s_avA + k*68 + dq);
      float wv = s_w[i*36 + k];
      acc.x += wv*a4.x; acc.y += wv*a4.y; acc.z += wv*a4.z; acc.w += wv*a4.w;
    }
    *(float4*)(s_S + i*68 + dq) = acc;
  } else if (t < 384) {
    const int tt2 = t - 128;
    const int mh = tt2 >> 7;                    // m-half
    const int i = (tt2 & 127) >> 4, dq = (tt2 & 15) << 2;
    float4 acc = {0,0,0,0};
    #pragma unroll 4
    for (int mm = 0; mm < 32; ++mm) {
      const int m = mh*32 + mm;
      float4 a4 = *(const float4*)(s_avO + m*68 + dq);
      float wv = s_wo[i*68 + m];
      acc.x += wv*a4.x; acc.y += wv*a4.y; acc.z += wv*a4.z; acc.w += wv*a4.w;
    }
    float* dst = mh ? (s_P + i*68 + dq) : (s_wavo + i*68 + dq);  // s_P = scratch
    *(float4*)dst = acc;
  }
  __syncthreads();

  // ---- ph8: base = S@Wf1a + (wavo0+wavo1)@Wf1b ---------------------------
  {
    const int h = t & 63, i = t >> 6;           // 512 threads = [8][64]
    float a0 = 0.f;
    #pragma unroll 4
    for (int d = 0; d < 64; ++d) {
      float w1v = W_f1[d*64 + h];
      float w2v = W_f1[(64 + d)*64 + h];
      a0 += s_S[i*68 + d]*w1v + (s_wavo[i*68 + d] + s_P[i*68 + d])*w2v;
    }
    s_base[i*68 + h] = a0;
  }
  __syncthreads();

  // ---- ph9: value[i][j] = sum_h lrelu(base[i,h]+w[i,j]*dproj[j,h])*Wf2[h] -
  // (i, j, h-half) per thread; halves combined via shfl_xor(32).
  {
    const int i = t >> 6, j = t & 31, half = (t >> 5) & 1;
    const float wij = s_w[i*36 + j];
    float acc = 0.f;
    #pragma unroll 4
    for (int hq = half*8; hq < half*8 + 8; ++hq) {
      float4 b4 = *(const float4*)(s_base + i*68 + hq*4);
      float4 d4 = *(const float4*)(s_dp + j*68 + hq*4);
      float4 f4 = *(const float4*)(s_wf2 + hq*4);
      float p0 = b4.x + wij*d4.x; p0 = p0 > 0.f ? p0 : 0.01f*p0;
      float p1 = b4.y + wij*d4.y; p1 = p1 > 0.f ? p1 : 0.01f*p1;
      float p2 = b4.z + wij*d4.z; p2 = p2 > 0.f ? p2 : 0.01f*p2;
      float p3 = b4.w + wij*d4.w; p3 = p3 > 0.f ? p3 : 0.01f*p3;
      acc += p0*f4.x + p1*f4.y + p2*f4.z + p3*f4.w;
    }
    acc += __shfl_xor(acc, 32, 64);
    if (half == 0)
      out[b*1024 + (i0 + i)*32 + j] = acc;
  }
}

extern "C" void kernel_launch(void* const* d_in, const int* in_sizes, int n_in,
                              void* d_out, int out_size, void* d_ws, size_t ws_size,
                              hipStream_t stream) {
  const float* states        = (const float*)d_in[0];
  const float* policies      = (const float*)d_in[1];
  const float* actions       = (const float*)d_in[2];
  const float* states_other  = (const float*)d_in[3];
  const float* actions_other = (const float*)d_in[4];
  const float* W_key         = (const float*)d_in[5];
  const float* W_query       = (const float*)d_in[6];
  const float* W_av          = (const float*)d_in[7];
  const float* W_key_other   = (const float*)d_in[8];
  const float* W_query_other = (const float*)d_in[9];
  const float* W_av_other    = (const float*)d_in[10];
  const float* W_f1          = (const float*)d_in[11];
  const float* W_f2          = (const float*)d_in[12];
  float* out = (float*)d_out;
  float* ws  = (float*)d_ws;   // 4.125 MB used

  k1_pre<<<800, 256, 0, stream>>>(states, policies, actions, states_other,
                                  actions_other, W_query, W_key,
                                  W_query_other, W_key_other, W_av, W_av_other,
                                  W_f1, ws);
  k2_main<<<512, 512, 0, stream>>>(states, states_other, W_f1, W_f2, ws, out);
}

// Round 3
// 128.144 us; speedup vs baseline: 1.0814x; 1.0814x over previous
//
#include <hip/hip_runtime.h>
#include <math.h>

// Problem constants (fixed by reference)
//  B=128, N=32, M=64, OBS=128, ACT=16, D_QK=128, D_AV=64, F_IN=144, H=64
// Outputs concatenated: value [B,32,32] @0, ret_weight [B,32,32] @131072,
// weight_other [B,32,64] @262144.
//
// Workspace (floats), 1,081,344 floats = 4.125 MB:
#define WS_WQK   0         // [128][128]
#define WS_WQKO  16384     // [128][128]
#define WS_AVA   32768     // [B][32][64]
#define WS_AVO   294912    // [B][64][64]
#define WS_DPROJ 819200    // [B][32][64]

#define INV_SQRT_DK 0.08838834764831845f  // 1/sqrt(128)

__device__ __forceinline__ float dot4(float4 a, float4 b) {
  return a.x*b.x + a.y*b.y + a.z*b.z + a.w*b.w;
}
__device__ __forceinline__ void fma4(float4& a, const float4 w, const float s) {
  a.x += w.x*s; a.y += w.y*s; a.z += w.z*s; a.w += w.w*s;
}

// ---------------------------------------------------------------------------
// K1: independent pre-work. grid 416:
//   [0,32)     Wqk / Wqko fusion tiles (32x32 out each)
//   [32,160)   avA + delta + dproj per b          (LDS-staged inputs)
//   [160,416)  avO per (b, m-half): 32 rows       (LDS-staged inputs)
// Inner loops: rows from LDS via uniform broadcast reads (cheap), weights
// from global coalesced (L2-hot, independent addresses -> deep pipeline).
// launch_bounds (256,2): give compiler VGPR headroom (round-2 showed VGPR=64
// under (256,4) -> zero load pipelining, 166 cyc/load serialization).
// ---------------------------------------------------------------------------
__global__ __launch_bounds__(256, 2) void k1_pre(
    const float* __restrict__ g_states, const float* __restrict__ g_pol,
    const float* __restrict__ g_act, const float* __restrict__ g_so,
    const float* __restrict__ g_ao,
    const float* __restrict__ Wq, const float* __restrict__ Wk,
    const float* __restrict__ Wqo, const float* __restrict__ Wko,
    const float* __restrict__ W_av, const float* __restrict__ W_avo,
    const float* __restrict__ W_f1, float* __restrict__ ws)
{
  __shared__ __align__(16) float pool[11904];   // 46.5 KB
  const int t = threadIdx.x;
  int blk = blockIdx.x;

  if (blk < 32) {
    // ---- weight fusion: Wqk[c][e] = sum_d Wq[c,d]*Wk[e,d] ----------------
    const float* A; const float* Bm; float* O;
    if (blk < 16) { A = Wq;  Bm = Wk;  O = ws + WS_WQK; }
    else          { A = Wqo; Bm = Wko; O = ws + WS_WQKO; blk -= 16; }
    const int tr = (blk >> 2) << 5;   // output row tile (c)
    const int tc = (blk & 3) << 5;    // output col tile (e)
    float* sA = pool;                 // [32][132]
    float* sB = pool + 4224;          // [32][132]
    const float4* a4 = (const float4*)(A + tr * 128);
    const float4* b4 = (const float4*)(Bm + tc * 128);
    #pragma unroll
    for (int u = 0; u < 4; ++u) {
      int f = t + u * 256;
      int r = f >> 5, c4 = f & 31;
      *(float4*)(sA + r*132 + c4*4) = a4[f];
      *(float4*)(sB + r*132 + c4*4) = b4[f];
    }
    __syncthreads();
    const int e = t & 31, cl0 = t >> 5;
    float acc[4] = {0,0,0,0};
    #pragma unroll 4
    for (int d4 = 0; d4 < 32; ++d4) {
      float4 bv = *(const float4*)(sB + e*132 + d4*4);
      #pragma unroll
      for (int rr = 0; rr < 4; ++rr) {
        float4 av = *(const float4*)(sA + (cl0 + rr*8)*132 + d4*4);
        acc[rr] += dot4(av, bv);
      }
    }
    #pragma unroll
    for (int rr = 0; rr < 4; ++rr)
      O[(tr + cl0 + rr*8)*128 + tc + e] = acc[rr];
    return;
  }
  blk -= 32;

  if (blk < 128) {
    // ---- avA + delta + dproj per b, inputs staged in LDS -----------------
    const int b = blk;
    float* s_in  = pool;            // [32][132] states
    float* s_t   = pool + 4224;     // [32][40]: actions @+0, policies @+20
    float* s_pre = pool + 5504;     // [32][132]: pre-act A @+0, P @+64
    float* s_dl  = pool + 9728;     // [32][68] delta
    {
      const float4* gs4 = (const float4*)(g_states + b*4096);
      #pragma unroll
      for (int u = 0; u < 4; ++u) {
        int f = t + u * 256;
        int r = f >> 5, c4 = f & 31;
        *(float4*)(s_in + r*132 + c4*4) = gs4[f];
      }
      if (t < 128) {
        int r = t >> 2, c4 = t & 3;
        *(float4*)(s_t + r*40 + c4*4) = ((const float4*)(g_act + b*512))[t];
      } else {
        int t2 = t - 128;
        int r = t2 >> 2, c4 = t2 & 3;
        *(float4*)(s_t + r*40 + 20 + c4*4) = ((const float4*)(g_pol + b*512))[t2];
      }
    }
    __syncthreads();
    {
      // wave = (ap, row-half 16); lane = d column. Rows: LDS broadcast.
      const int wv_  = t >> 6;
      const int ap   = wv_ & 1;         // 0 = actions, 1 = policies
      const int rh   = wv_ >> 1;        // row half (16 rows)
      const int lane = t & 63;
      const float* s_rows = s_in + rh*16*132;
      const float* s_tl   = s_t + rh*16*40 + ap*20;
      float acc[16];
      #pragma unroll
      for (int r = 0; r < 16; ++r) acc[r] = 0.f;
      #pragma unroll 4
      for (int c4 = 0; c4 < 32; ++c4) {           // shared c < 128
        const float w0 = W_av[(c4*4+0)*64 + lane];
        const float w1 = W_av[(c4*4+1)*64 + lane];
        const float w2 = W_av[(c4*4+2)*64 + lane];
        const float w3 = W_av[(c4*4+3)*64 + lane];
        #pragma unroll
        for (int r = 0; r < 16; ++r) {
          float4 sv = *(const float4*)(s_rows + r*132 + c4*4);  // LDS bcast
          acc[r] += sv.x*w0 + sv.y*w1 + sv.z*w2 + sv.w*w3;
        }
      }
      #pragma unroll
      for (int c4 = 0; c4 < 4; ++c4) {            // tail c in [128,144)
        const float w0 = W_av[(128 + c4*4+0)*64 + lane];
        const float w1 = W_av[(128 + c4*4+1)*64 + lane];
        const float w2 = W_av[(128 + c4*4+2)*64 + lane];
        const float w3 = W_av[(128 + c4*4+3)*64 + lane];
        #pragma unroll
        for (int r = 0; r < 16; ++r) {
          float4 sv = *(const float4*)(s_tl + r*40 + c4*4);     // LDS bcast
          acc[r] += sv.x*w0 + sv.y*w1 + sv.z*w2 + sv.w*w3;
        }
      }
      #pragma unroll
      for (int r = 0; r < 16; ++r)
        s_pre[(rh*16 + r)*132 + ap*64 + lane] = acc[r];
    }
    __syncthreads();
    {
      // combine: avA = tanh(preA); delta = tanh(preP) - avA; 8 floats/thread
      const int r = t >> 3, d0 = (t & 7) << 3;
      float4 a0 = *(const float4*)(s_pre + r*132 + d0);
      float4 a1 = *(const float4*)(s_pre + r*132 + d0 + 4);
      float4 p0 = *(const float4*)(s_pre + r*132 + 64 + d0);
      float4 p1 = *(const float4*)(s_pre + r*132 + 64 + d0 + 4);
      float4 va0, va1, dl0, dl1;
      va0.x = tanhf(a0.x); va0.y = tanhf(a0.y); va0.z = tanhf(a0.z); va0.w = tanhf(a0.w);
      va1.x = tanhf(a1.x); va1.y = tanhf(a1.y); va1.z = tanhf(a1.z); va1.w = tanhf(a1.w);
      dl0.x = tanhf(p0.x) - va0.x; dl0.y = tanhf(p0.y) - va0.y;
      dl0.z = tanhf(p0.z) - va0.z; dl0.w = tanhf(p0.w) - va0.w;
      dl1.x = tanhf(p1.x) - va1.x; dl1.y = tanhf(p1.y) - va1.y;
      dl1.z = tanhf(p1.z) - va1.z; dl1.w = tanhf(p1.w) - va1.w;
      *(float4*)(ws + WS_AVA + b*2048 + r*64 + d0)     = va0;
      *(float4*)(ws + WS_AVA + b*2048 + r*64 + d0 + 4) = va1;
      *(float4*)(s_dl + r*68 + d0)     = dl0;
      *(float4*)(s_dl + r*68 + d0 + 4) = dl1;
    }
    __syncthreads();
    {
      // dproj[j][h] = sum_d delta[j][d] * W_f1[d][h]; 8 rows/thread
      const int h = t & 63;
      const int j0 = (t >> 6) << 3;
      float acc[8] = {0,0,0,0,0,0,0,0};
      #pragma unroll 4
      for (int d4 = 0; d4 < 16; ++d4) {
        float w0 = W_f1[(d4*4+0)*64 + h];
        float w1 = W_f1[(d4*4+1)*64 + h];
        float w2 = W_f1[(d4*4+2)*64 + h];
        float w3 = W_f1[(d4*4+3)*64 + h];
        #pragma unroll
        for (int q = 0; q < 8; ++q) {
          float4 dv = *(const float4*)(s_dl + (j0+q)*68 + d4*4);  // LDS bcast
          acc[q] += dv.x*w0 + dv.y*w1 + dv.z*w2 + dv.w*w3;
        }
      }
      #pragma unroll
      for (int q = 0; q < 8; ++q)
        ws[WS_DPROJ + b*2048 + (j0+q)*64 + h] = acc[q];
    }
    return;
  }
  blk -= 128;

  // ---- avO per (b, m-half): 32 rows, inputs staged in LDS ----------------
  {
    const int b = blk >> 1, m0 = (blk & 1) << 5;
    float* s_so = pool;            // [32][132]
    float* s_ao = pool + 4224;     // [32][20]
    {
      const float4* gso4 = (const float4*)(g_so + (b*64 + m0) * 128);
      #pragma unroll
      for (int u = 0; u < 4; ++u) {
        int f = t + u * 256;
        int r = f >> 5, c4 = f & 31;
        *(float4*)(s_so + r*132 + c4*4) = gso4[f];
      }
      if (t < 128) {
        int r = t >> 2, c4 = t & 3;
        *(float4*)(s_ao + r*20 + c4*4) = ((const float4*)(g_ao + (b*64 + m0)*16))[t];
      }
    }
    __syncthreads();
    const int wv_  = t >> 6;            // 0..3: 8-row group
    const int lane = t & 63;
    const float* s_rows = s_so + wv_*8*132;
    const float* s_tl   = s_ao + wv_*8*20;
    float acc[8];
    #pragma unroll
    for (int r = 0; r < 8; ++r) acc[r] = 0.f;
    #pragma unroll 4
    for (int c4 = 0; c4 < 32; ++c4) {
      const float w0 = W_avo[(c4*4+0)*64 + lane];
      const float w1 = W_avo[(c4*4+1)*64 + lane];
      const float w2 = W_avo[(c4*4+2)*64 + lane];
      const float w3 = W_avo[(c4*4+3)*64 + lane];
      #pragma unroll
      for (int r = 0; r < 8; ++r) {
        float4 sv = *(const float4*)(s_rows + r*132 + c4*4);   // LDS bcast
        acc[r] += sv.x*w0 + sv.y*w1 + sv.z*w2 + sv.w*w3;
      }
    }
    #pragma unroll
    for (int c4 = 0; c4 < 4; ++c4) {
      const float w0 = W_avo[(128 + c4*4+0)*64 + lane];
      const float w1 = W_avo[(128 + c4*4+1)*64 + lane];
      const float w2 = W_avo[(128 + c4*4+2)*64 + lane];
      const float w3 = W_avo[(128 + c4*4+3)*64 + lane];
      #pragma unroll
      for (int r = 0; r < 8; ++r) {
        float4 sv = *(const float4*)(s_tl + r*20 + c4*4);      // LDS bcast
        acc[r] += sv.x*w0 + sv.y*w1 + sv.z*w2 + sv.w*w3;
      }
    }
    #pragma unroll
    for (int r = 0; r < 8; ++r)
      ws[WS_AVO + b*4096 + (m0 + wv_*8 + r)*64 + lane] = tanhf(acc[r]);
  }
}

// ---------------------------------------------------------------------------
// K2: everything after pre-work, per (b, i-octile). grid 512 x 512 threads.
// Round-2 fix: ph2 reads its state rows from LDS (staged in ph1) instead of
// wave-uniform GLOBAL loads -> removes the per-iteration VMEM latency chain.
// LDS pool (floats), 17472 = 68.25 KB (2 blocks/CU):
//   A    @0     [4352]: states [32][132] / so tiles [32][132] / avO [64][68]
//   RED  @4352  [8448]: ph2 partials [4][8][66]xf4; later avA[32][68]@4352,
//                        dproj [32][68] @6528
//   P    @12800 [2144]: [8][268]  (P1 cols 0..127, P2 cols 128..255);
//                        scratch for wavo partial (mh=1) in ph7
//   w    @14944 [288] : [8][36]
//   wo   @15232 [544] : [8][68]
//   S    @15776 [544] : [8][68]
//   wavo @16320 [544]
//   base @16864 [544]
//   wf2  @17408 [64]
// ---------------------------------------------------------------------------
__global__ __launch_bounds__(512, 4) void k2_main(
    const float* __restrict__ g_states, const float* __restrict__ g_so,
    const float* __restrict__ W_f1, const float* __restrict__ W_f2,
    const float* __restrict__ ws, float* __restrict__ out)
{
  __shared__ __align__(16) float pool[17472];
  float* s_st   = pool;
  float* s_red  = pool + 4352;
  float* s_avA  = pool + 4352;     // alias RED (dead after ph2 reduce)
  float* s_dp   = pool + 6528;     // alias RED
  float* s_avO  = pool;            // alias A (dead after ph5)
  float* s_P    = pool + 12800;
  float* s_w    = pool + 14944;
  float* s_wo   = pool + 15232;
  float* s_S    = pool + 15776;
  float* s_wavo = pool + 16320;
  float* s_base = pool + 16864;
  float* s_wf2  = pool + 17408;

  const int t = threadIdx.x;
  const int b = blockIdx.x >> 2;
  const int i0 = (blockIdx.x & 3) << 3;

  // ---- ph1: stage states (read by ph2 rows + ph3 j-side), wf2 ------------
  {
    const float4* gs4 = (const float4*)(g_states + b * 4096);
    #pragma unroll
    for (int u = 0; u < 2; ++u) {
      int f = t + u * 512;
      int r = f >> 5, c4 = f & 31;
      *(float4*)(s_st + r*132 + c4*4) = gs4[f];
    }
    if (t < 16) *(float4*)(s_wf2 + t*4) = ((const float4*)W_f2)[t];
  }
  __syncthreads();   // ph2 reads s_st now

  // ---- ph2: P = states[i0..+8] @ [Wqk|Wqko] ------------------------------
  // wave = (K-chunk, row-half); lane = f4-column of [P1|P2]. Rows from LDS
  // broadcast; weights from ws global (coalesced, L2-hot, prefetchable).
  {
    const int wave = t >> 6;             // 0..7
    const int kc   = wave & 3;           // K chunk (32 c each)
    const int rh   = wave >> 2;          // row half (4 rows)
    const int col  = t & 63;             // <32: Wqk/P1, >=32: Wqko/P2
    const float* Wp = (col < 32) ? (ws + WS_WQK + col*4)
                                 : (ws + WS_WQKO + (col-32)*4);
    const float* srow = s_st + (i0 + rh*4)*132 + kc*32;
    float4 acc[4];
    #pragma unroll
    for (int r = 0; r < 4; ++r) acc[r] = make_float4(0.f,0.f,0.f,0.f);
    #pragma unroll 2
    for (int c4 = 0; c4 < 8; ++c4) {
      float4 sv[4];
      #pragma unroll
      for (int r = 0; r < 4; ++r)
        sv[r] = *(const float4*)(srow + r*132 + c4*4);    // LDS broadcast
      #pragma unroll
      for (int k = 0; k < 4; ++k) {
        float4 wv = *(const float4*)(Wp + (kc*32 + c4*4 + k)*128);
        #pragma unroll
        for (int r = 0; r < 4; ++r)
          fma4(acc[r], wv, ((const float*)&sv[r])[k]);
      }
    }
    #pragma unroll
    for (int r = 0; r < 4; ++r)
      *(float4*)(s_red + ((kc*8 + rh*4 + r)*66 + col)*4) = acc[r];
  }
  __syncthreads();
  {
    // reduce 4 K-chunk partials -> P [8][268]; 512 threads = [8 rows][64 f4]
    const int r = t >> 6, col = t & 63;
    float4 a0 = *(const float4*)(s_red + ((0*8 + r)*66 + col)*4);
    float4 a1 = *(const float4*)(s_red + ((1*8 + r)*66 + col)*4);
    float4 a2 = *(const float4*)(s_red + ((2*8 + r)*66 + col)*4);
    float4 a3 = *(const float4*)(s_red + ((3*8 + r)*66 + col)*4);
    float4 s4;
    s4.x = (a0.x + a1.x) + (a2.x + a3.x);
    s4.y = (a0.y + a1.y) + (a2.y + a3.y);
    s4.z = (a0.z + a1.z) + (a2.z + a3.z);
    s4.w = (a0.w + a1.w) + (a2.w + a3.w);
    *(float4*)(s_P + r*268 + col*4) = s4;
  }
  __syncthreads();

  // ---- ph3: self scores + register softmax + write ret_weight ------------
  // (r, j, e-half) per thread; halves combined via shfl_xor(32).
  {
    const int r = t >> 6, j = t & 31, half = (t >> 5) & 1;
    const int e0 = half << 4;
    float acc = 0.f;
    #pragma unroll 8
    for (int e4 = 0; e4 < 16; ++e4) {
      float4 p4  = *(const float4*)(s_P + r*268 + (e0 + e4)*4);
      float4 st4 = *(const float4*)(s_st + j*132 + (e0 + e4)*4);
      acc += dot4(p4, st4);
    }
    acc += __shfl_xor(acc, 32, 64);
    acc *= INV_SQRT_DK;
    float mx = acc;
    for (int off = 16; off; off >>= 1) mx = fmaxf(mx, __shfl_xor(mx, off, 32));
    float ev = __expf(acc - mx);
    float sum = ev;
    for (int off = 16; off; off >>= 1) sum += __shfl_xor(sum, off, 32);
    float wn = ev / sum;
    if (half == 0) {
      out[131072 + b*1024 + (i0 + r)*32 + j] = wn;
      s_w[r*36 + j] = wn;
    }
  }
  __syncthreads();   // protect s_st reads from ph4's overwrite

  // ---- ph4/5: other scores over two states_other tiles -------------------
  for (int tt = 0; tt < 2; ++tt) {
    const float4* gt4 = (const float4*)(g_so + (b*64 + tt*32) * 128);
    #pragma unroll
    for (int u = 0; u < 2; ++u) {
      int f = t + u * 512;
      int r = f >> 5, c4 = f & 31;
      *(float4*)(s_st + r*132 + c4*4) = gt4[f];
    }
    __syncthreads();
    const int r = t >> 6, m = t & 31, half = (t >> 5) & 1;
    const int c0 = half << 4;
    float acc = 0.f;
    #pragma unroll 8
    for (int c4 = 0; c4 < 16; ++c4) {
      float4 p4  = *(const float4*)(s_P + r*268 + 128 + (c0 + c4)*4);
      float4 st4 = *(const float4*)(s_st + m*132 + (c0 + c4)*4);
      acc += dot4(p4, st4);
    }
    acc += __shfl_xor(acc, 32, 64);
    if (half == 0) s_wo[r*68 + tt*32 + m] = acc * INV_SQRT_DK;
    __syncthreads();
  }

  // ---- ph6: softmax wo + write weight_other; stage avA/avO/dproj ---------
  {
    const int r = t >> 6, l = t & 63;          // 512 threads = [8][64]
    float v = s_wo[r*68 + l];
    float mx = v;
    for (int off = 32; off; off >>= 1) mx = fmaxf(mx, __shfl_xor(mx, off, 64));
    float ev = __expf(v - mx);
    float sum = ev;
    for (int off = 32; off; off >>= 1) sum += __shfl_xor(sum, off, 64);
    float wn = ev / sum;
    out[262144 + b*2048 + (i0 + r)*64 + l] = wn;
    s_wo[r*68 + l] = wn;
  }
  {
    int f = t;                                  // 512 f4 each
    int k = f >> 4, dq = f & 15;
    *(float4*)(s_avA + k*68 + dq*4) = ((const float4*)(ws + WS_AVA + b*2048))[f];
    *(float4*)(s_dp  + k*68 + dq*4) = ((const float4*)(ws + WS_DPROJ + b*2048))[f];
  }
  #pragma unroll
  for (int u = 0; u < 2; ++u) {
    int f = t + u * 512;
    int m = f >> 4, dq = f & 15;
    *(float4*)(s_avO + m*68 + dq*4) = ((const float4*)(ws + WS_AVO + b*4096))[f];
  }
  __syncthreads();

  // ---- ph7: S = w @ avA (t<128); wavo = wo @ avO split over m (t<384) ----
  if (t < 128) {
    const int i = t >> 4, dq = (t & 15) << 2;
    float4 acc = {0,0,0,0};
    #pragma unroll 4
    for (int k = 0; k < 32; ++k) {
      float4 a4 = *(const float4*)(s_avA + k*68 + dq);
      float wv = s_w[i*36 + k];
      acc.x += wv*a4.x; acc.y += wv*a4.y; acc.z += wv*a4.z; acc.w += wv*a4.w;
    }
    *(float4*)(s_S + i*68 + dq) = acc;
  } else if (t < 384) {
    const int tt2 = t - 128;
    const int mh = tt2 >> 7;                    // m-half
    const int i = (tt2 & 127) >> 4, dq = (tt2 & 15) << 2;
    float4 acc = {0,0,0,0};
    #pragma unroll 4
    for (int mm = 0; mm < 32; ++mm) {
      const int m = mh*32 + mm;
      float4 a4 = *(const float4*)(s_avO + m*68 + dq);
      float wv = s_wo[i*68 + m];
      acc.x += wv*a4.x; acc.y += wv*a4.y; acc.z += wv*a4.z; acc.w += wv*a4.w;
    }
    float* dst = mh ? (s_P + i*68 + dq) : (s_wavo + i*68 + dq);  // s_P = scratch
    *(float4*)dst = acc;
  }
  __syncthreads();

  // ---- ph8: base = S@Wf1a + (wavo0+wavo1)@Wf1b ---------------------------
  {
    const int h = t & 63, i = t >> 6;           // 512 threads = [8][64]
    float a0 = 0.f;
    #pragma unroll 4
    for (int d = 0; d < 64; ++d) {
      float w1v = W_f1[d*64 + h];
      float w2v = W_f1[(64 + d)*64 + h];
      a0 += s_S[i*68 + d]*w1v + (s_wavo[i*68 + d] + s_P[i*68 + d])*w2v;
    }
    s_base[i*68 + h] = a0;
  }
  __syncthreads();

  // ---- ph9: value[i][j] = sum_h lrelu(base[i,h]+w[i,j]*dproj[j,h])*Wf2[h] -
  // (i, j, h-half) per thread; halves combined via shfl_xor(32).
  {
    const int i = t >> 6, j = t & 31, half = (t >> 5) & 1;
    const float wij = s_w[i*36 + j];
    float acc = 0.f;
    #pragma unroll 4
    for (int hq = half*8; hq < half*8 + 8; ++hq) {
      float4 b4 = *(const float4*)(s_base + i*68 + hq*4);
      float4 d4 = *(const float4*)(s_dp + j*68 + hq*4);
      float4 f4 = *(const float4*)(s_wf2 + hq*4);
      float p0 = b4.x + wij*d4.x; p0 = p0 > 0.f ? p0 : 0.01f*p0;
      float p1 = b4.y + wij*d4.y; p1 = p1 > 0.f ? p1 : 0.01f*p1;
      float p2 = b4.z + wij*d4.z; p2 = p2 > 0.f ? p2 : 0.01f*p2;
      float p3 = b4.w + wij*d4.w; p3 = p3 > 0.f ? p3 : 0.01f*p3;
      acc += p0*f4.x + p1*f4.y + p2*f4.z + p3*f4.w;
    }
    acc += __shfl_xor(acc, 32, 64);
    if (half == 0)
      out[b*1024 + (i0 + i)*32 + j] = acc;
  }
}

extern "C" void kernel_launch(void* const* d_in, const int* in_sizes, int n_in,
                              void* d_out, int out_size, void* d_ws, size_t ws_size,
                              hipStream_t stream) {
  const float* states        = (const float*)d_in[0];
  const float* policies      = (const float*)d_in[1];
  const float* actions       = (const float*)d_in[2];
  const float* states_other  = (const float*)d_in[3];
  const float* actions_other = (const float*)d_in[4];
  const float* W_key         = (const float*)d_in[5];
  const float* W_query       = (const float*)d_in[6];
  const float* W_av          = (const float*)d_in[7];
  const float* W_key_other   = (const float*)d_in[8];
  const float* W_query_other = (const float*)d_in[9];
  const float* W_av_other    = (const float*)d_in[10];
  const float* W_f1          = (const float*)d_in[11];
  const float* W_f2          = (const float*)d_in[12];
  float* out = (float*)d_out;
  float* ws  = (float*)d_ws;   // 4.125 MB used

  k1_pre<<<416, 256, 0, stream>>>(states, policies, actions, states_other,
                                  actions_other, W_query, W_key,
                                  W_query_other, W_key_other, W_av, W_av_other,
                                  W_f1, ws);
  k2_main<<<512, 512, 0, stream>>>(states, states_other, W_f1, W_f2, ws, out);
}

// Round 4
// 120.063 us; speedup vs baseline: 1.1542x; 1.0673x over previous
//
#include <hip/hip_runtime.h>
#include <math.h>

// Problem constants (fixed by reference)
//  B=128, N=32, M=64, OBS=128, ACT=16, D_QK=128, D_AV=64, F_IN=144, H=64
// Outputs concatenated: value [B,32,32] @0, ret_weight [B,32,32] @131072,
// weight_other [B,32,64] @262144.
//
// Workspace (floats), 1,081,344 floats = 4.125 MB:
#define WS_WQK   0         // [128][128]
#define WS_WQKO  16384     // [128][128]
#define WS_AVA   32768     // [B][32][64]
#define WS_AVO   294912    // [B][64][64]
#define WS_DPROJ 819200    // [B][32][64]

#define INV_SQRT_DK 0.08838834764831845f  // 1/sqrt(128)

__device__ __forceinline__ float dot4(float4 a, float4 b) {
  return a.x*b.x + a.y*b.y + a.z*b.z + a.w*b.w;
}
__device__ __forceinline__ void fma4(float4& a, const float4 w, const float s) {
  a.x += w.x*s; a.y += w.y*s; a.z += w.z*s; a.w += w.w*s;
}

// ---------------------------------------------------------------------------
// K1: independent pre-work. grid 800 (3.1 blocks/CU; round-3's 416 = 1.6/CU
// left L2 weight-load latency unhidden at ~1.6 waves/SIMD):
//   [0,32)     Wqk / Wqko fusion tiles (32x32 out each)
//   [32,288)   avA + delta + dproj per (b, j-half): 16 rows, LDS-staged rows
//   [288,800)  avO per (b, m-quarter): 16 rows, LDS-staged rows
// Inner loops: rows from LDS uniform broadcast (cheap, conflict-free),
// weights from global coalesced (L2-hot, independent addrs -> pipelined).
// (256,2): VGPR cap 128 (round-2's (256,4)->VGPR=64 killed load pipelining).
// ---------------------------------------------------------------------------
__global__ __launch_bounds__(256, 2) void k1_pre(
    const float* __restrict__ g_states, const float* __restrict__ g_pol,
    const float* __restrict__ g_act, const float* __restrict__ g_so,
    const float* __restrict__ g_ao,
    const float* __restrict__ Wq, const float* __restrict__ Wk,
    const float* __restrict__ Wqo, const float* __restrict__ Wko,
    const float* __restrict__ W_av, const float* __restrict__ W_avo,
    const float* __restrict__ W_f1, float* __restrict__ ws)
{
  __shared__ __align__(16) float pool[8448];   // 33 KB
  const int t = threadIdx.x;
  int blk = blockIdx.x;

  if (blk < 32) {
    // ---- weight fusion: Wqk[c][e] = sum_d Wq[c,d]*Wk[e,d] ----------------
    const float* A; const float* Bm; float* O;
    if (blk < 16) { A = Wq;  Bm = Wk;  O = ws + WS_WQK; }
    else          { A = Wqo; Bm = Wko; O = ws + WS_WQKO; blk -= 16; }
    const int tr = (blk >> 2) << 5;   // output row tile (c)
    const int tc = (blk & 3) << 5;    // output col tile (e)
    float* sA = pool;                 // [32][132]
    float* sB = pool + 4224;          // [32][132]
    const float4* a4 = (const float4*)(A + tr * 128);
    const float4* b4 = (const float4*)(Bm + tc * 128);
    #pragma unroll
    for (int u = 0; u < 4; ++u) {
      int f = t + u * 256;
      int r = f >> 5, c4 = f & 31;
      *(float4*)(sA + r*132 + c4*4) = a4[f];
      *(float4*)(sB + r*132 + c4*4) = b4[f];
    }
    __syncthreads();
    const int e = t & 31, cl0 = t >> 5;
    float acc[4] = {0,0,0,0};
    #pragma unroll 4
    for (int d4 = 0; d4 < 32; ++d4) {
      float4 bv = *(const float4*)(sB + e*132 + d4*4);
      #pragma unroll
      for (int rr = 0; rr < 4; ++rr) {
        float4 av = *(const float4*)(sA + (cl0 + rr*8)*132 + d4*4);
        acc[rr] += dot4(av, bv);
      }
    }
    #pragma unroll
    for (int rr = 0; rr < 4; ++rr)
      O[(tr + cl0 + rr*8)*128 + tc + e] = acc[rr];
    return;
  }
  blk -= 32;

  if (blk < 256) {
    // ---- avA + delta + dproj per (b, j-half): 16 rows, LDS-staged --------
    const int b  = blk >> 1;
    const int jh = blk & 1;
    float* s_in  = pool;            // [16][132] states rows jh*16..+16
    float* s_t   = pool + 2112;     // [16][40]: actions @+0, policies @+20
    float* s_pre = pool + 2752;     // [16][132]: pre-act A @+0, P @+64
    float* s_dl  = pool + 4864;     // [16][68] delta
    {
      const float4* gs4 = (const float4*)(g_states + b*4096 + jh*2048);
      #pragma unroll
      for (int u = 0; u < 2; ++u) {
        int f = t + u * 256;
        int r = f >> 5, c4 = f & 31;
        *(float4*)(s_in + r*132 + c4*4) = gs4[f];
      }
      if (t < 64) {
        int r = t >> 2, c4 = t & 3;
        *(float4*)(s_t + r*40 + c4*4) =
            ((const float4*)(g_act + b*512 + jh*256))[t];
      } else if (t < 128) {
        int t2 = t - 64;
        int r = t2 >> 2, c4 = t2 & 3;
        *(float4*)(s_t + r*40 + 20 + c4*4) =
            ((const float4*)(g_pol + b*512 + jh*256))[t2];
      }
    }
    __syncthreads();
    {
      // wave = (ap, 8-row group); lane = d column. Rows via LDS broadcast.
      const int wv_  = t >> 6;
      const int ap   = wv_ & 1;         // 0 = actions, 1 = policies
      const int rq   = wv_ >> 1;        // 8-row group
      const int lane = t & 63;
      const float* s_rows = s_in + rq*8*132;
      const float* s_tl   = s_t + rq*8*40 + ap*20;
      float acc[8];
      #pragma unroll
      for (int r = 0; r < 8; ++r) acc[r] = 0.f;
      #pragma unroll 4
      for (int c4 = 0; c4 < 32; ++c4) {           // shared c < 128
        const float w0 = W_av[(c4*4+0)*64 + lane];
        const float w1 = W_av[(c4*4+1)*64 + lane];
        const float w2 = W_av[(c4*4+2)*64 + lane];
        const float w3 = W_av[(c4*4+3)*64 + lane];
        #pragma unroll
        for (int r = 0; r < 8; ++r) {
          float4 sv = *(const float4*)(s_rows + r*132 + c4*4);  // LDS bcast
          acc[r] += sv.x*w0 + sv.y*w1 + sv.z*w2 + sv.w*w3;
        }
      }
      #pragma unroll
      for (int c4 = 0; c4 < 4; ++c4) {            // tail c in [128,144)
        const float w0 = W_av[(128 + c4*4+0)*64 + lane];
        const float w1 = W_av[(128 + c4*4+1)*64 + lane];
        const float w2 = W_av[(128 + c4*4+2)*64 + lane];
        const float w3 = W_av[(128 + c4*4+3)*64 + lane];
        #pragma unroll
        for (int r = 0; r < 8; ++r) {
          float4 sv = *(const float4*)(s_tl + r*40 + c4*4);     // LDS bcast
          acc[r] += sv.x*w0 + sv.y*w1 + sv.z*w2 + sv.w*w3;
        }
      }
      #pragma unroll
      for (int r = 0; r < 8; ++r)
        s_pre[(rq*8 + r)*132 + ap*64 + lane] = acc[r];
    }
    __syncthreads();
    {
      // combine: avA = tanh(preA); delta = tanh(preP) - avA; 4 floats/thread
      const int r = t >> 4, d0 = (t & 15) << 2;   // 16 rows x 16 f4-cols
      float4 a0 = *(const float4*)(s_pre + r*132 + d0);
      float4 p0 = *(const float4*)(s_pre + r*132 + 64 + d0);
      float4 va0, dl0;
      va0.x = tanhf(a0.x); va0.y = tanhf(a0.y); va0.z = tanhf(a0.z); va0.w = tanhf(a0.w);
      dl0.x = tanhf(p0.x) - va0.x; dl0.y = tanhf(p0.y) - va0.y;
      dl0.z = tanhf(p0.z) - va0.z; dl0.w = tanhf(p0.w) - va0.w;
      *(float4*)(ws + WS_AVA + b*2048 + (jh*16 + r)*64 + d0) = va0;
      *(float4*)(s_dl + r*68 + d0) = dl0;
    }
    __syncthreads();
    {
      // dproj[j][h] = sum_d delta[j][d] * W_f1[d][h]; 4 rows/thread
      const int h = t & 63;
      const int j0 = (t >> 6) << 2;
      float acc[4] = {0,0,0,0};
      #pragma unroll 4
      for (int d4 = 0; d4 < 16; ++d4) {
        float w0 = W_f1[(d4*4+0)*64 + h];
        float w1 = W_f1[(d4*4+1)*64 + h];
        float w2 = W_f1[(d4*4+2)*64 + h];
        float w3 = W_f1[(d4*4+3)*64 + h];
        #pragma unroll
        for (int q = 0; q < 4; ++q) {
          float4 dv = *(const float4*)(s_dl + (j0+q)*68 + d4*4);  // LDS bcast
          acc[q] += dv.x*w0 + dv.y*w1 + dv.z*w2 + dv.w*w3;
        }
      }
      #pragma unroll
      for (int q = 0; q < 4; ++q)
        ws[WS_DPROJ + b*2048 + (jh*16 + j0+q)*64 + h] = acc[q];
    }
    return;
  }
  blk -= 256;

  // ---- avO per (b, m-quarter): 16 rows, LDS-staged -----------------------
  {
    const int b = blk >> 2, m0 = (blk & 3) << 4;
    float* s_so = pool;            // [16][132]
    float* s_ao = pool + 2112;     // [16][20]
    {
      const float4* gso4 = (const float4*)(g_so + (b*64 + m0) * 128);
      #pragma unroll
      for (int u = 0; u < 2; ++u) {
        int f = t + u * 256;
        int r = f >> 5, c4 = f & 31;
        *(float4*)(s_so + r*132 + c4*4) = gso4[f];
      }
      if (t < 64) {
        int r = t >> 2, c4 = t & 3;
        *(float4*)(s_ao + r*20 + c4*4) =
            ((const float4*)(g_ao + (b*64 + m0)*16))[t];
      }
    }
    __syncthreads();
    const int wv_  = t >> 6;            // 0..3: 4-row group
    const int lane = t & 63;
    const float* s_rows = s_so + wv_*4*132;
    const float* s_tl   = s_ao + wv_*4*20;
    float acc[4] = {0.f, 0.f, 0.f, 0.f};
    #pragma unroll 4
    for (int c4 = 0; c4 < 32; ++c4) {
      const float w0 = W_avo[(c4*4+0)*64 + lane];
      const float w1 = W_avo[(c4*4+1)*64 + lane];
      const float w2 = W_avo[(c4*4+2)*64 + lane];
      const float w3 = W_avo[(c4*4+3)*64 + lane];
      #pragma unroll
      for (int r = 0; r < 4; ++r) {
        float4 sv = *(const float4*)(s_rows + r*132 + c4*4);   // LDS bcast
        acc[r] += sv.x*w0 + sv.y*w1 + sv.z*w2 + sv.w*w3;
      }
    }
    #pragma unroll
    for (int c4 = 0; c4 < 4; ++c4) {
      const float w0 = W_avo[(128 + c4*4+0)*64 + lane];
      const float w1 = W_avo[(128 + c4*4+1)*64 + lane];
      const float w2 = W_avo[(128 + c4*4+2)*64 + lane];
      const float w3 = W_avo[(128 + c4*4+3)*64 + lane];
      #pragma unroll
      for (int r = 0; r < 4; ++r) {
        float4 sv = *(const float4*)(s_tl + r*20 + c4*4);      // LDS bcast
        acc[r] += sv.x*w0 + sv.y*w1 + sv.z*w2 + sv.w*w3;
      }
    }
    #pragma unroll
    for (int r = 0; r < 4; ++r)
      ws[WS_AVO + b*4096 + (m0 + wv_*4 + r)*64 + lane] = tanhf(acc[r]);
  }
}

// ---------------------------------------------------------------------------
// K2: everything after pre-work, per (b, i-octile). grid 512 x 512 threads.
// ph2 reads state rows from LDS (staged in ph1); weights from ws (L2-hot).
// LDS pool (floats), 17472 = 68.25 KB (2 blocks/CU):
//   A    @0     [4352]: states [32][132] / so tiles [32][132] / avO [64][68]
//   RED  @4352  [8448]: ph2 partials [4][8][66]xf4; later avA[32][68]@4352,
//                        dproj [32][68] @6528
//   P    @12800 [2144]: [8][268]  (P1 cols 0..127, P2 cols 128..255);
//                        scratch for wavo partial (mh=1) in ph7
//   w    @14944 [288] : [8][36]
//   wo   @15232 [544] : [8][68]
//   S    @15776 [544] : [8][68]
//   wavo @16320 [544]
//   base @16864 [544]
//   wf2  @17408 [64]
// ---------------------------------------------------------------------------
__global__ __launch_bounds__(512, 4) void k2_main(
    const float* __restrict__ g_states, const float* __restrict__ g_so,
    const float* __restrict__ W_f1, const float* __restrict__ W_f2,
    const float* __restrict__ ws, float* __restrict__ out)
{
  __shared__ __align__(16) float pool[17472];
  float* s_st   = pool;
  float* s_red  = pool + 4352;
  float* s_avA  = pool + 4352;     // alias RED (dead after ph2 reduce)
  float* s_dp   = pool + 6528;     // alias RED
  float* s_avO  = pool;            // alias A (dead after ph5)
  float* s_P    = pool + 12800;
  float* s_w    = pool + 14944;
  float* s_wo   = pool + 15232;
  float* s_S    = pool + 15776;
  float* s_wavo = pool + 16320;
  float* s_base = pool + 16864;
  float* s_wf2  = pool + 17408;

  const int t = threadIdx.x;
  const int b = blockIdx.x >> 2;
  const int i0 = (blockIdx.x & 3) << 3;

  // ---- ph1: stage states (read by ph2 rows + ph3 j-side), wf2 ------------
  {
    const float4* gs4 = (const float4*)(g_states + b * 4096);
    #pragma unroll
    for (int u = 0; u < 2; ++u) {
      int f = t + u * 512;
      int r = f >> 5, c4 = f & 31;
      *(float4*)(s_st + r*132 + c4*4) = gs4[f];
    }
    if (t < 16) *(float4*)(s_wf2 + t*4) = ((const float4*)W_f2)[t];
  }
  __syncthreads();   // ph2 reads s_st now

  // ---- ph2: P = states[i0..+8] @ [Wqk|Wqko] ------------------------------
  // wave = (K-chunk, row-half); lane = f4-column of [P1|P2]. Rows from LDS
  // broadcast; weights from ws global (coalesced, L2-hot, prefetchable).
  {
    const int wave = t >> 6;             // 0..7
    const int kc   = wave & 3;           // K chunk (32 c each)
    const int rh   = wave >> 2;          // row half (4 rows)
    const int col  = t & 63;             // <32: Wqk/P1, >=32: Wqko/P2
    const float* Wp = (col < 32) ? (ws + WS_WQK + col*4)
                                 : (ws + WS_WQKO + (col-32)*4);
    const float* srow = s_st + (i0 + rh*4)*132 + kc*32;
    float4 acc[4];
    #pragma unroll
    for (int r = 0; r < 4; ++r) acc[r] = make_float4(0.f,0.f,0.f,0.f);
    #pragma unroll 2
    for (int c4 = 0; c4 < 8; ++c4) {
      float4 sv[4];
      #pragma unroll
      for (int r = 0; r < 4; ++r)
        sv[r] = *(const float4*)(srow + r*132 + c4*4);    // LDS broadcast
      #pragma unroll
      for (int k = 0; k < 4; ++k) {
        float4 wv = *(const float4*)(Wp + (kc*32 + c4*4 + k)*128);
        #pragma unroll
        for (int r = 0; r < 4; ++r)
          fma4(acc[r], wv, ((const float*)&sv[r])[k]);
      }
    }
    #pragma unroll
    for (int r = 0; r < 4; ++r)
      *(float4*)(s_red + ((kc*8 + rh*4 + r)*66 + col)*4) = acc[r];
  }
  __syncthreads();
  {
    // reduce 4 K-chunk partials -> P [8][268]; 512 threads = [8 rows][64 f4]
    const int r = t >> 6, col = t & 63;
    float4 a0 = *(const float4*)(s_red + ((0*8 + r)*66 + col)*4);
    float4 a1 = *(const float4*)(s_red + ((1*8 + r)*66 + col)*4);
    float4 a2 = *(const float4*)(s_red + ((2*8 + r)*66 + col)*4);
    float4 a3 = *(const float4*)(s_red + ((3*8 + r)*66 + col)*4);
    float4 s4;
    s4.x = (a0.x + a1.x) + (a2.x + a3.x);
    s4.y = (a0.y + a1.y) + (a2.y + a3.y);
    s4.z = (a0.z + a1.z) + (a2.z + a3.z);
    s4.w = (a0.w + a1.w) + (a2.w + a3.w);
    *(float4*)(s_P + r*268 + col*4) = s4;
  }
  __syncthreads();

  // ---- ph3: self scores + register softmax + write ret_weight ------------
  // (r, j, e-half) per thread; halves combined via shfl_xor(32).
  {
    const int r = t >> 6, j = t & 31, half = (t >> 5) & 1;
    const int e0 = half << 4;
    float acc = 0.f;
    #pragma unroll 8
    for (int e4 = 0; e4 < 16; ++e4) {
      float4 p4  = *(const float4*)(s_P + r*268 + (e0 + e4)*4);
      float4 st4 = *(const float4*)(s_st + j*132 + (e0 + e4)*4);
      acc += dot4(p4, st4);
    }
    acc += __shfl_xor(acc, 32, 64);
    acc *= INV_SQRT_DK;
    float mx = acc;
    for (int off = 16; off; off >>= 1) mx = fmaxf(mx, __shfl_xor(mx, off, 32));
    float ev = __expf(acc - mx);
    float sum = ev;
    for (int off = 16; off; off >>= 1) sum += __shfl_xor(sum, off, 32);
    float wn = ev / sum;
    if (half == 0) {
      out[131072 + b*1024 + (i0 + r)*32 + j] = wn;
      s_w[r*36 + j] = wn;
    }
  }
  __syncthreads();   // protect s_st reads from ph4's overwrite

  // ---- ph4/5: other scores over two states_other tiles -------------------
  for (int tt = 0; tt < 2; ++tt) {
    const float4* gt4 = (const float4*)(g_so + (b*64 + tt*32) * 128);
    #pragma unroll
    for (int u = 0; u < 2; ++u) {
      int f = t + u * 512;
      int r = f >> 5, c4 = f & 31;
      *(float4*)(s_st + r*132 + c4*4) = gt4[f];
    }
    __syncthreads();
    const int r = t >> 6, m = t & 31, half = (t >> 5) & 1;
    const int c0 = half << 4;
    float acc = 0.f;
    #pragma unroll 8
    for (int c4 = 0; c4 < 16; ++c4) {
      float4 p4  = *(const float4*)(s_P + r*268 + 128 + (c0 + c4)*4);
      float4 st4 = *(const float4*)(s_st + m*132 + (c0 + c4)*4);
      acc += dot4(p4, st4);
    }
    acc += __shfl_xor(acc, 32, 64);
    if (half == 0) s_wo[r*68 + tt*32 + m] = acc * INV_SQRT_DK;
    __syncthreads();
  }

  // ---- ph6: softmax wo + write weight_other; stage avA/avO/dproj ---------
  {
    const int r = t >> 6, l = t & 63;          // 512 threads = [8][64]
    float v = s_wo[r*68 + l];
    float mx = v;
    for (int off = 32; off; off >>= 1) mx = fmaxf(mx, __shfl_xor(mx, off, 64));
    float ev = __expf(v - mx);
    float sum = ev;
    for (int off = 32; off; off >>= 1) sum += __shfl_xor(sum, off, 64);
    float wn = ev / sum;
    out[262144 + b*2048 + (i0 + r)*64 + l] = wn;
    s_wo[r*68 + l] = wn;
  }
  {
    int f = t;                                  // 512 f4 each
    int k = f >> 4, dq = f & 15;
    *(float4*)(s_avA + k*68 + dq*4) = ((const float4*)(ws + WS_AVA + b*2048))[f];
    *(float4*)(s_dp  + k*68 + dq*4) = ((const float4*)(ws + WS_DPROJ + b*2048))[f];
  }
  #pragma unroll
  for (int u = 0; u < 2; ++u) {
    int f = t + u * 512;
    int m = f >> 4, dq = f & 15;
    *(float4*)(s_avO + m*68 + dq*4) = ((const float4*)(ws + WS_AVO + b*4096))[f];
  }
  __syncthreads();

  // ---- ph7: S = w @ avA (t<128); wavo = wo @ avO split over m (t<384) ----
  if (t < 128) {
    const int i = t >> 4, dq = (t & 15) << 2;
    float4 acc = {0,0,0,0};
    #pragma unroll 4
    for (int k = 0; k < 32; ++k) {
      float4 a4 = *(const float4*)(s_avA + k*68 + dq);
      float wv = s_w[i*36 + k];
      acc.x += wv*a4.x; acc.y += wv*a4.y; acc.z += wv*a4.z; acc.w += wv*a4.w;
    }
    *(float4*)(s_S + i*68 + dq) = acc;
  } else if (t < 384) {
    const int tt2 = t - 128;
    const int mh = tt2 >> 7;                    // m-half
    const int i = (tt2 & 127) >> 4, dq = (tt2 & 15) << 2;
    float4 acc = {0,0,0,0};
    #pragma unroll 4
    for (int mm = 0; mm < 32; ++mm) {
      const int m = mh*32 + mm;
      float4 a4 = *(const float4*)(s_avO + m*68 + dq);
      float wv = s_wo[i*68 + m];
      acc.x += wv*a4.x; acc.y += wv*a4.y; acc.z += wv*a4.z; acc.w += wv*a4.w;
    }
    float* dst = mh ? (s_P + i*68 + dq) : (s_wavo + i*68 + dq);  // s_P = scratch
    *(float4*)dst = acc;
  }
  __syncthreads();

  // ---- ph8: base = S@Wf1a + (wavo0+wavo1)@Wf1b ---------------------------
  {
    const int h = t & 63, i = t >> 6;           // 512 threads = [8][64]
    float a0 = 0.f;
    #pragma unroll 4
    for (int d = 0; d < 64; ++d) {
      float w1v = W_f1[d*64 + h];
      float w2v = W_f1[(64 + d)*64 + h];
      a0 += s_S[i*68 + d]*w1v + (s_wavo[i*68 + d] + s_P[i*68 + d])*w2v;
    }
    s_base[i*68 + h] = a0;
  }
  __syncthreads();

  // ---- ph9: value[i][j] = sum_h lrelu(base[i,h]+w[i,j]*dproj[j,h])*Wf2[h] -
  // (i, j, h-half) per thread; halves combined via shfl_xor(32).
  {
    const int i = t >> 6, j = t & 31, half = (t >> 5) & 1;
    const float wij = s_w[i*36 + j];
    float acc = 0.f;
    #pragma unroll 4
    for (int hq = half*8; hq < half*8 + 8; ++hq) {
      float4 b4 = *(const float4*)(s_base + i*68 + hq*4);
      float4 d4 = *(const float4*)(s_dp + j*68 + hq*4);
      float4 f4 = *(const float4*)(s_wf2 + hq*4);
      float p0 = b4.x + wij*d4.x; p0 = p0 > 0.f ? p0 : 0.01f*p0;
      float p1 = b4.y + wij*d4.y; p1 = p1 > 0.f ? p1 : 0.01f*p1;
      float p2 = b4.z + wij*d4.z; p2 = p2 > 0.f ? p2 : 0.01f*p2;
      float p3 = b4.w + wij*d4.w; p3 = p3 > 0.f ? p3 : 0.01f*p3;
      acc += p0*f4.x + p1*f4.y + p2*f4.z + p3*f4.w;
    }
    acc += __shfl_xor(acc, 32, 64);
    if (half == 0)
      out[b*1024 + (i0 + i)*32 + j] = acc;
  }
}

extern "C" void kernel_launch(void* const* d_in, const int* in_sizes, int n_in,
                              void* d_out, int out_size, void* d_ws, size_t ws_size,
                              hipStream_t stream) {
  const float* states        = (const float*)d_in[0];
  const float* policies      = (const float*)d_in[1];
  const float* actions       = (const float*)d_in[2];
  const float* states_other  = (const float*)d_in[3];
  const float* actions_other = (const float*)d_in[4];
  const float* W_key         = (const float*)d_in[5];
  const float* W_query       = (const float*)d_in[6];
  const float* W_av          = (const float*)d_in[7];
  const float* W_key_other   = (const float*)d_in[8];
  const float* W_query_other = (const float*)d_in[9];
  const float* W_av_other    = (const float*)d_in[10];
  const float* W_f1          = (const float*)d_in[11];
  const float* W_f2          = (const float*)d_in[12];
  float* out = (float*)d_out;
  float* ws  = (float*)d_ws;   // 4.125 MB used

  k1_pre<<<800, 256, 0, stream>>>(states, policies, actions, states_other,
                                  actions_other, W_query, W_key,
                                  W_query_other, W_key_other, W_av, W_av_other,
                                  W_f1, ws);
  k2_main<<<512, 512, 0, stream>>>(states, states_other, W_f1, W_f2, ws, out);
}

// Round 5
// 114.479 us; speedup vs baseline: 1.2105x; 1.0488x over previous
//
#include <hip/hip_runtime.h>
#include <math.h>

// Problem constants (fixed by reference)
//  B=128, N=32, M=64, OBS=128, ACT=16, D_QK=128, D_AV=64, F_IN=144, H=64
// Outputs concatenated: value [B,32,32] @0, ret_weight [B,32,32] @131072,
// weight_other [B,32,64] @262144.
//
// Workspace (floats), 1,081,344 floats = 4.125 MB:
#define WS_WQK   0         // [128][128]
#define WS_WQKO  16384     // [128][128]
#define WS_AVA   32768     // [B][32][64]
#define WS_AVO   294912    // [B][64][64]
#define WS_DPROJ 819200    // [B][32][64]

#define INV_SQRT_DK 0.08838834764831845f  // 1/sqrt(128)

// XOR bank swizzle: rows colliding mod 8 get distinct low f4-column bits.
// Banks for lane-row j at f4-col c: (4j + 4*((c ^ (j>>3)) & mask)) % 32 ->
// the {j, j+8, j+16, j+24(,..+56)} octet maps to distinct banks.
#define SWZ32(row, c) (((c) ^ ((row) >> 3)) & 31)
#define SWZ16(row, c) (((c) ^ ((row) >> 3)) & 15)

__device__ __forceinline__ float dot4(float4 a, float4 b) {
  return a.x*b.x + a.y*b.y + a.z*b.z + a.w*b.w;
}
__device__ __forceinline__ void fma4(float4& a, const float4 w, const float s) {
  a.x += w.x*s; a.y += w.y*s; a.z += w.z*s; a.w += w.w*s;
}

// ---------------------------------------------------------------------------
// K1: independent pre-work. grid 1056 (~4.1 blocks/CU pipeline depth):
//   [0,32)      Wqk / Wqko fusion tiles (32x32 out each)
//   [32,544)    avA + delta + dproj per (b, j-quarter): 8 rows, LDS-staged
//   [544,1056)  avO per (b, m-quarter): 16 rows, LDS-staged
// Inner loops: rows from LDS uniform broadcast (conflict-free), weights from
// global coalesced (L2-hot). (256,2): VGPR headroom for load pipelining.
// ---------------------------------------------------------------------------
__global__ __launch_bounds__(256, 2) void k1_pre(
    const float* __restrict__ g_states, const float* __restrict__ g_pol,
    const float* __restrict__ g_act, const float* __restrict__ g_so,
    const float* __restrict__ g_ao,
    const float* __restrict__ Wq, const float* __restrict__ Wk,
    const float* __restrict__ Wqo, const float* __restrict__ Wko,
    const float* __restrict__ W_av, const float* __restrict__ W_avo,
    const float* __restrict__ W_f1, float* __restrict__ ws)
{
  __shared__ __align__(16) float pool[8448];   // 33 KB
  const int t = threadIdx.x;
  int blk = blockIdx.x;

  if (blk < 32) {
    // ---- weight fusion: Wqk[c][e] = sum_d Wq[c,d]*Wk[e,d] ----------------
    const float* A; const float* Bm; float* O;
    if (blk < 16) { A = Wq;  Bm = Wk;  O = ws + WS_WQK; }
    else          { A = Wqo; Bm = Wko; O = ws + WS_WQKO; blk -= 16; }
    const int tr = (blk >> 2) << 5;   // output row tile (c)
    const int tc = (blk & 3) << 5;    // output col tile (e)
    float* sA = pool;                 // [32][132]
    float* sB = pool + 4224;          // [32][132]
    const float4* a4 = (const float4*)(A + tr * 128);
    const float4* b4 = (const float4*)(Bm + tc * 128);
    #pragma unroll
    for (int u = 0; u < 4; ++u) {
      int f = t + u * 256;
      int r = f >> 5, c4 = f & 31;
      *(float4*)(sA + r*132 + c4*4) = a4[f];
      *(float4*)(sB + r*132 + c4*4) = b4[f];
    }
    __syncthreads();
    const int e = t & 31, cl0 = t >> 5;
    float acc[4] = {0,0,0,0};
    #pragma unroll 4
    for (int d4 = 0; d4 < 32; ++d4) {
      float4 bv = *(const float4*)(sB + e*132 + d4*4);
      #pragma unroll
      for (int rr = 0; rr < 4; ++rr) {
        float4 av = *(const float4*)(sA + (cl0 + rr*8)*132 + d4*4);
        acc[rr] += dot4(av, bv);
      }
    }
    #pragma unroll
    for (int rr = 0; rr < 4; ++rr)
      O[(tr + cl0 + rr*8)*128 + tc + e] = acc[rr];
    return;
  }
  blk -= 32;

  if (blk < 512) {
    // ---- avA + delta + dproj per (b, j-quarter): 8 rows ------------------
    const int b  = blk >> 2;
    const int jq = blk & 3;            // rows jq*8 .. +8
    float* s_in  = pool;               // [8][132] states
    float* s_t   = pool + 1056;        // [8][40]: actions @+0, policies @+20
    float* s_pre = pool + 1376;        // [8][132]: pre-act A @+0, P @+64
    float* s_dl  = pool + 2432;        // [8][68] delta
    {
      const float4* gs4 = (const float4*)(g_states + b*4096 + jq*1024);
      int r = t >> 5, c4 = t & 31;
      *(float4*)(s_in + r*132 + c4*4) = gs4[t];
      if (t < 32) {
        int rr = t >> 2, cc = t & 3;
        *(float4*)(s_t + rr*40 + cc*4) =
            ((const float4*)(g_act + b*512 + jq*128))[t];
      } else if (t < 64) {
        int t2 = t - 32;
        int rr = t2 >> 2, cc = t2 & 3;
        *(float4*)(s_t + rr*40 + 20 + cc*4) =
            ((const float4*)(g_pol + b*512 + jq*128))[t2];
      }
    }
    __syncthreads();
    {
      // wave = (ap, 4-row group); lane = d column. Rows via LDS broadcast.
      const int wv_  = t >> 6;
      const int ap   = wv_ & 1;         // 0 = actions, 1 = policies
      const int rq   = wv_ >> 1;        // 4-row group
      const int lane = t & 63;
      const float* s_rows = s_in + rq*4*132;
      const float* s_tl   = s_t + rq*4*40 + ap*20;
      float acc[4] = {0,0,0,0};
      #pragma unroll 4
      for (int c4 = 0; c4 < 32; ++c4) {           // shared c < 128
        const float w0 = W_av[(c4*4+0)*64 + lane];
        const float w1 = W_av[(c4*4+1)*64 + lane];
        const float w2 = W_av[(c4*4+2)*64 + lane];
        const float w3 = W_av[(c4*4+3)*64 + lane];
        #pragma unroll
        for (int r = 0; r < 4; ++r) {
          float4 sv = *(const float4*)(s_rows + r*132 + c4*4);  // LDS bcast
          acc[r] += sv.x*w0 + sv.y*w1 + sv.z*w2 + sv.w*w3;
        }
      }
      #pragma unroll
      for (int c4 = 0; c4 < 4; ++c4) {            // tail c in [128,144)
        const float w0 = W_av[(128 + c4*4+0)*64 + lane];
        const float w1 = W_av[(128 + c4*4+1)*64 + lane];
        const float w2 = W_av[(128 + c4*4+2)*64 + lane];
        const float w3 = W_av[(128 + c4*4+3)*64 + lane];
        #pragma unroll
        for (int r = 0; r < 4; ++r) {
          float4 sv = *(const float4*)(s_tl + r*40 + c4*4);     // LDS bcast
          acc[r] += sv.x*w0 + sv.y*w1 + sv.z*w2 + sv.w*w3;
        }
      }
      #pragma unroll
      for (int r = 0; r < 4; ++r)
        s_pre[(rq*4 + r)*132 + ap*64 + lane] = acc[r];
    }
    __syncthreads();
    if (t < 128) {
      // combine: avA = tanh(preA); delta = tanh(preP) - avA; 1 f4 each
      const int r = t >> 4, d0 = (t & 15) << 2;   // 8 rows x 16 f4-cols
      float4 a0 = *(const float4*)(s_pre + r*132 + d0);
      float4 p0 = *(const float4*)(s_pre + r*132 + 64 + d0);
      float4 va0, dl0;
      va0.x = tanhf(a0.x); va0.y = tanhf(a0.y); va0.z = tanhf(a0.z); va0.w = tanhf(a0.w);
      dl0.x = tanhf(p0.x) - va0.x; dl0.y = tanhf(p0.y) - va0.y;
      dl0.z = tanhf(p0.z) - va0.z; dl0.w = tanhf(p0.w) - va0.w;
      *(float4*)(ws + WS_AVA + b*2048 + (jq*8 + r)*64 + d0) = va0;
      *(float4*)(s_dl + r*68 + d0) = dl0;
    }
    __syncthreads();
    {
      // dproj[j][h] = sum_d delta[j][d] * W_f1[d][h]; 2 rows/thread
      const int h = t & 63;
      const int j0 = (t >> 6) << 1;
      float acc[2] = {0,0};
      #pragma unroll 4
      for (int d4 = 0; d4 < 16; ++d4) {
        float w0 = W_f1[(d4*4+0)*64 + h];
        float w1 = W_f1[(d4*4+1)*64 + h];
        float w2 = W_f1[(d4*4+2)*64 + h];
        float w3 = W_f1[(d4*4+3)*64 + h];
        #pragma unroll
        for (int q = 0; q < 2; ++q) {
          float4 dv = *(const float4*)(s_dl + (j0+q)*68 + d4*4);  // LDS bcast
          acc[q] += dv.x*w0 + dv.y*w1 + dv.z*w2 + dv.w*w3;
        }
      }
      #pragma unroll
      for (int q = 0; q < 2; ++q)
        ws[WS_DPROJ + b*2048 + (jq*8 + j0+q)*64 + h] = acc[q];
    }
    return;
  }
  blk -= 512;

  // ---- avO per (b, m-quarter): 16 rows, LDS-staged -----------------------
  {
    const int b = blk >> 2, m0 = (blk & 3) << 4;
    float* s_so = pool;            // [16][132]
    float* s_ao = pool + 2112;     // [16][20]
    {
      const float4* gso4 = (const float4*)(g_so + (b*64 + m0) * 128);
      #pragma unroll
      for (int u = 0; u < 2; ++u) {
        int f = t + u * 256;
        int r = f >> 5, c4 = f & 31;
        *(float4*)(s_so + r*132 + c4*4) = gso4[f];
      }
      if (t < 64) {
        int r = t >> 2, c4 = t & 3;
        *(float4*)(s_ao + r*20 + c4*4) =
            ((const float4*)(g_ao + (b*64 + m0)*16))[t];
      }
    }
    __syncthreads();
    const int wv_  = t >> 6;            // 0..3: 4-row group
    const int lane = t & 63;
    const float* s_rows = s_so + wv_*4*132;
    const float* s_tl   = s_ao + wv_*4*20;
    float acc[4] = {0.f, 0.f, 0.f, 0.f};
    #pragma unroll 4
    for (int c4 = 0; c4 < 32; ++c4) {
      const float w0 = W_avo[(c4*4+0)*64 + lane];
      const float w1 = W_avo[(c4*4+1)*64 + lane];
      const float w2 = W_avo[(c4*4+2)*64 + lane];
      const float w3 = W_avo[(c4*4+3)*64 + lane];
      #pragma unroll
      for (int r = 0; r < 4; ++r) {
        float4 sv = *(const float4*)(s_rows + r*132 + c4*4);   // LDS bcast
        acc[r] += sv.x*w0 + sv.y*w1 + sv.z*w2 + sv.w*w3;
      }
    }
    #pragma unroll
    for (int c4 = 0; c4 < 4; ++c4) {
      const float w0 = W_avo[(128 + c4*4+0)*64 + lane];
      const float w1 = W_avo[(128 + c4*4+1)*64 + lane];
      const float w2 = W_avo[(128 + c4*4+2)*64 + lane];
      const float w3 = W_avo[(128 + c4*4+3)*64 + lane];
      #pragma unroll
      for (int r = 0; r < 4; ++r) {
        float4 sv = *(const float4*)(s_tl + r*20 + c4*4);      // LDS bcast
        acc[r] += sv.x*w0 + sv.y*w1 + sv.z*w2 + sv.w*w3;
      }
    }
    #pragma unroll
    for (int r = 0; r < 4; ++r)
      ws[WS_AVO + b*4096 + (m0 + wv_*4 + r)*64 + lane] = tanhf(acc[r]);
  }
}

// ---------------------------------------------------------------------------
// K2: everything after pre-work, per (b, i-octile). grid 512 x 512 threads.
// Round-4 changes: (a) XOR bank-swizzle on all row-strided b128 reads
// (s_st / s_so / s_dp were 8-way conflicted: bank stride 4*row mod 32),
// (b) ph4/5 merged: both so-tiles staged once into the dead RED region with
// loads issued BEFORE ph3 (HBM latency hides under ph3 compute); 3 barriers
// removed, (c) launch_bounds (512,2) — LDS caps residency at 2 blocks/CU
// anyway, so the VGPR cap was pure downside.
// LDS pool (floats), 17472 = 68.25 KB (2 blocks/CU):
//   A    @0     [4352]: states [32][132] swz / avO [64][68] (after ph3)
//   RED  @4352  [8448]: ph2 partials [4][8][66]xf4; then so [64][132] swz;
//                        then avA[32][68]@4352, dproj[32][68]swz @6528
//   P    @12800 [2144]: [8][268]; scratch for wavo partial (mh=1) in ph7
//   w    @14944 [288] : [8][36]
//   wo   @15232 [544] : [8][68]
//   S    @15776 [544] : [8][68]
//   wavo @16320 [544]
//   base @16864 [544]
//   wf2  @17408 [64]
// ---------------------------------------------------------------------------
__global__ __launch_bounds__(512, 2) void k2_main(
    const float* __restrict__ g_states, const float* __restrict__ g_so,
    const float* __restrict__ W_f1, const float* __restrict__ W_f2,
    const float* __restrict__ ws, float* __restrict__ out)
{
  __shared__ __align__(16) float pool[17472];
  float* s_st   = pool;
  float* s_red  = pool + 4352;
  float* s_so   = pool + 4352;     // alias RED (dead after ph2 reduce)
  float* s_avA  = pool + 4352;     // alias RED (dead after ph4)
  float* s_dp   = pool + 6528;     // alias RED
  float* s_avO  = pool;            // alias A (dead after ph3)
  float* s_P    = pool + 12800;
  float* s_w    = pool + 14944;
  float* s_wo   = pool + 15232;
  float* s_S    = pool + 15776;
  float* s_wavo = pool + 16320;
  float* s_base = pool + 16864;
  float* s_wf2  = pool + 17408;

  const int t = threadIdx.x;
  const int b = blockIdx.x >> 2;
  const int i0 = (blockIdx.x & 3) << 3;

  // ---- ph1: stage states (swizzled; read by ph2 rows + ph3 j-side), wf2 --
  {
    const float4* gs4 = (const float4*)(g_states + b * 4096);
    #pragma unroll
    for (int u = 0; u < 2; ++u) {
      int f = t + u * 512;
      int r = f >> 5, c4 = f & 31;
      *(float4*)(s_st + r*132 + 4*SWZ32(r, c4)) = gs4[f];
    }
    if (t < 16) *(float4*)(s_wf2 + t*4) = ((const float4*)W_f2)[t];
  }
  __syncthreads();

  // ---- ph2: P = states[i0..+8] @ [Wqk|Wqko] ------------------------------
  // wave = (K-chunk, row-half); lane = f4-column of [P1|P2]. Rows from LDS
  // broadcast (swizzle uniform per block: rows i0..i0+7 share row>>3).
  {
    const int wave = t >> 6;             // 0..7
    const int kc   = wave & 3;           // K chunk (32 c each)
    const int rh   = wave >> 2;          // row half (4 rows)
    const int col  = t & 63;             // <32: Wqk/P1, >=32: Wqko/P2
    const float* Wp = (col < 32) ? (ws + WS_WQK + col*4)
                                 : (ws + WS_WQKO + (col-32)*4);
    const int rbase = i0 + rh*4;
    const int rsw   = i0 >> 3;           // rows i0..i0+7 share this
    float4 acc[4];
    #pragma unroll
    for (int r = 0; r < 4; ++r) acc[r] = make_float4(0.f,0.f,0.f,0.f);
    #pragma unroll 2
    for (int c4 = 0; c4 < 8; ++c4) {
      const int colw = 4*(((kc*8 + c4) ^ rsw) & 31);
      float4 sv[4];
      #pragma unroll
      for (int r = 0; r < 4; ++r)
        sv[r] = *(const float4*)(s_st + (rbase + r)*132 + colw);  // bcast
      #pragma unroll
      for (int k = 0; k < 4; ++k) {
        float4 wv = *(const float4*)(Wp + (kc*32 + c4*4 + k)*128);
        #pragma unroll
        for (int r = 0; r < 4; ++r)
          fma4(acc[r], wv, ((const float*)&sv[r])[k]);
      }
    }
    #pragma unroll
    for (int r = 0; r < 4; ++r)
      *(float4*)(s_red + ((kc*8 + rh*4 + r)*66 + col)*4) = acc[r];
  }
  __syncthreads();
  {
    // reduce 4 K-chunk partials -> P [8][268]; contiguous access (no swz)
    const int r = t >> 6, col = t & 63;
    float4 a0 = *(const float4*)(s_red + ((0*8 + r)*66 + col)*4);
    float4 a1 = *(const float4*)(s_red + ((1*8 + r)*66 + col)*4);
    float4 a2 = *(const float4*)(s_red + ((2*8 + r)*66 + col)*4);
    float4 a3 = *(const float4*)(s_red + ((3*8 + r)*66 + col)*4);
    float4 s4;
    s4.x = (a0.x + a1.x) + (a2.x + a3.x);
    s4.y = (a0.y + a1.y) + (a2.y + a3.y);
    s4.z = (a0.z + a1.z) + (a2.z + a3.z);
    s4.w = (a0.w + a1.w) + (a2.w + a3.w);
    *(float4*)(s_P + r*268 + col*4) = s4;
  }
  __syncthreads();

  // ---- ph3: self scores + register softmax + write ret_weight.
  //      In parallel: issue so-tile loads early, write to LDS after compute
  //      (RED is dead now; HBM latency hides under ph3's VALU work). --------
  float4 stg[4];
  {
    const float4* gso4 = (const float4*)(g_so + b * 64 * 128);
    #pragma unroll
    for (int u = 0; u < 4; ++u) stg[u] = gso4[t + u*512];
  }
  {
    const int r = t >> 6, j = t & 31, half = (t >> 5) & 1;
    const int e0 = half << 4;
    float acc = 0.f;
    #pragma unroll 8
    for (int e4 = 0; e4 < 16; ++e4) {
      float4 p4  = *(const float4*)(s_P + r*268 + (e0 + e4)*4);
      float4 st4 = *(const float4*)(s_st + j*132 + 4*SWZ32(j, e0 + e4));
      acc += dot4(p4, st4);
    }
    acc += __shfl_xor(acc, 32, 64);
    acc *= INV_SQRT_DK;
    float mx = acc;
    for (int off = 16; off; off >>= 1) mx = fmaxf(mx, __shfl_xor(mx, off, 32));
    float ev = __expf(acc - mx);
    float sum = ev;
    for (int off = 16; off; off >>= 1) sum += __shfl_xor(sum, off, 32);
    float wn = ev / sum;
    if (half == 0) {
      out[131072 + b*1024 + (i0 + r)*32 + j] = wn;
      s_w[r*36 + j] = wn;
    }
  }
  {
    // write staged so-tiles into RED (swizzled)
    #pragma unroll
    for (int u = 0; u < 4; ++u) {
      int f = t + u * 512;
      int m = f >> 5, c4 = f & 31;
      *(float4*)(s_so + m*132 + 4*SWZ32(m, c4)) = stg[u];
    }
  }
  __syncthreads();

  // ---- ph4: other scores, all 64 m in one phase --------------------------
  {
    const int r = t >> 6, m = t & 63;    // 512 threads = [8][64]
    float acc = 0.f;
    #pragma unroll 8
    for (int c4 = 0; c4 < 32; ++c4) {
      float4 p4  = *(const float4*)(s_P + r*268 + 128 + c4*4);          // bcast
      float4 so4 = *(const float4*)(s_so + m*132 + 4*SWZ32(m, c4));     // swz
      acc += dot4(p4, so4);
    }
    s_wo[r*68 + m] = acc * INV_SQRT_DK;
  }
  __syncthreads();

  // ---- ph6: softmax wo + write weight_other; stage avA/avO/dproj ---------
  {
    const int r = t >> 6, l = t & 63;          // 512 threads = [8][64]
    float v = s_wo[r*68 + l];
    float mx = v;
    for (int off = 32; off; off >>= 1) mx = fmaxf(mx, __shfl_xor(mx, off, 64));
    float ev = __expf(v - mx);
    float sum = ev;
    for (int off = 32; off; off >>= 1) sum += __shfl_xor(sum, off, 64);
    float wn = ev / sum;
    out[262144 + b*2048 + (i0 + r)*64 + l] = wn;
    s_wo[r*68 + l] = wn;
  }
  {
    int k = t >> 4, dq = t & 15;                // 512 f4 each
    *(float4*)(s_avA + k*68 + dq*4) = ((const float4*)(ws + WS_AVA + b*2048))[t];
    *(float4*)(s_dp  + k*68 + 4*SWZ16(k, dq)) =
        ((const float4*)(ws + WS_DPROJ + b*2048))[t];
  }
  #pragma unroll
  for (int u = 0; u < 2; ++u) {
    int f = t + u * 512;
    int m = f >> 4, dq = f & 15;
    *(float4*)(s_avO + m*68 + dq*4) = ((const float4*)(ws + WS_AVO + b*4096))[f];
  }
  __syncthreads();

  // ---- ph7: S = w @ avA (t<128); wavo = wo @ avO split over m (t<384) ----
  if (t < 128) {
    const int i = t >> 4, dq = (t & 15) << 2;
    float4 acc = {0,0,0,0};
    #pragma unroll 4
    for (int k = 0; k < 32; ++k) {
      float4 a4 = *(const float4*)(s_avA + k*68 + dq);   // row-addr: bcast
      float wv = s_w[i*36 + k];
      acc.x += wv*a4.x; acc.y += wv*a4.y; acc.z += wv*a4.z; acc.w += wv*a4.w;
    }
    *(float4*)(s_S + i*68 + dq) = acc;
  } else if (t < 384) {
    const int tt2 = t - 128;
    const int mh = tt2 >> 7;                    // m-half
    const int i = (tt2 & 127) >> 4, dq = (tt2 & 15) << 2;
    float4 acc = {0,0,0,0};
    #pragma unroll 4
    for (int mm = 0; mm < 32; ++mm) {
      const int m = mh*32 + mm;
      float4 a4 = *(const float4*)(s_avO + m*68 + dq);   // row-addr: bcast
      float wv = s_wo[i*68 + m];
      acc.x += wv*a4.x; acc.y += wv*a4.y; acc.z += wv*a4.z; acc.w += wv*a4.w;
    }
    float* dst = mh ? (s_P + i*68 + dq) : (s_wavo + i*68 + dq);  // s_P scratch
    *(float4*)dst = acc;
  }
  __syncthreads();

  // ---- ph8: base = S@Wf1a + (wavo0+wavo1)@Wf1b ---------------------------
  {
    const int h = t & 63, i = t >> 6;           // 512 threads = [8][64]
    float a0 = 0.f;
    #pragma unroll 4
    for (int d = 0; d < 64; ++d) {
      float w1v = W_f1[d*64 + h];
      float w2v = W_f1[(64 + d)*64 + h];
      a0 += s_S[i*68 + d]*w1v + (s_wavo[i*68 + d] + s_P[i*68 + d])*w2v;
    }
    s_base[i*68 + h] = a0;
  }
  __syncthreads();

  // ---- ph9: value[i][j] = sum_h lrelu(base[i,h]+w[i,j]*dproj[j,h])*Wf2[h] -
  // (i, j, h-half) per thread; halves combined via shfl_xor(32).
  {
    const int i = t >> 6, j = t & 31, half = (t >> 5) & 1;
    const float wij = s_w[i*36 + j];
    float acc = 0.f;
    #pragma unroll 4
    for (int hq = half*8; hq < half*8 + 8; ++hq) {
      float4 b4 = *(const float4*)(s_base + i*68 + hq*4);              // bcast
      float4 d4 = *(const float4*)(s_dp + j*68 + 4*SWZ16(j, hq));      // swz
      float4 f4 = *(const float4*)(s_wf2 + hq*4);
      float p0 = b4.x + wij*d4.x; p0 = p0 > 0.f ? p0 : 0.01f*p0;
      float p1 = b4.y + wij*d4.y; p1 = p1 > 0.f ? p1 : 0.01f*p1;
      float p2 = b4.z + wij*d4.z; p2 = p2 > 0.f ? p2 : 0.01f*p2;
      float p3 = b4.w + wij*d4.w; p3 = p3 > 0.f ? p3 : 0.01f*p3;
      acc += p0*f4.x + p1*f4.y + p2*f4.z + p3*f4.w;
    }
    acc += __shfl_xor(acc, 32, 64);
    if (half == 0)
      out[b*1024 + (i0 + i)*32 + j] = acc;
  }
}

extern "C" void kernel_launch(void* const* d_in, const int* in_sizes, int n_in,
                              void* d_out, int out_size, void* d_ws, size_t ws_size,
                              hipStream_t stream) {
  const float* states        = (const float*)d_in[0];
  const float* policies      = (const float*)d_in[1];
  const float* actions       = (const float*)d_in[2];
  const float* states_other  = (const float*)d_in[3];
  const float* actions_other = (const float*)d_in[4];
  const float* W_key         = (const float*)d_in[5];
  const float* W_query       = (const float*)d_in[6];
  const float* W_av          = (const float*)d_in[7];
  const float* W_key_other   = (const float*)d_in[8];
  const float* W_query_other = (const float*)d_in[9];
  const float* W_av_other    = (const float*)d_in[10];
  const float* W_f1          = (const float*)d_in[11];
  const float* W_f2          = (const float*)d_in[12];
  float* out = (float*)d_out;
  float* ws  = (float*)d_ws;   // 4.125 MB used

  k1_pre<<<1056, 256, 0, stream>>>(states, policies, actions, states_other,
                                   actions_other, W_query, W_key,
                                   W_query_other, W_key_other, W_av, W_av_other,
                                   W_f1, ws);
  k2_main<<<512, 512, 0, stream>>>(states, states_other, W_f1, W_f2, ws, out);
}